// Round 6
// baseline (2078.004 us; speedup 1.0000x reference)
//
#include <hip/hip_runtime.h>
#include <hip/hip_bf16.h>
#include <cstddef>

// Problem constants (fixed by setup_inputs)
#define TOTAL   1536
#define HIDDEN  1024
#define HK      8
#define HV      16
#define DK      64
#define DV      64
#define KSZ     4
#define KEY_DIM 512
#define VAL_DIM 1024
#define CONV_DIM 2048
#define NSEQ    4

// LDS strides (floats) for the chunk kernel
#define SK 68   // KlT/QlT row stride (272B, 16B-aligned, 2-way banks max)
#define SS 68   // S0l / Am / G0 stride

// ---------------------------------------------------------------------------
// GEMM: C[M,N] = A[M,K] @ B[N,K]^T, fp32. 64x64 tile, BK=16, 256 thr, 4x4 micro.
// ---------------------------------------------------------------------------
__global__ __launch_bounds__(256) void gemm_tn(const float* __restrict__ A,
                                               const float* __restrict__ B,
                                               float* __restrict__ C,
                                               int M, int N, int K) {
    __shared__ float As[16][68];
    __shared__ float Bs[16][68];
    const int tid = threadIdx.x;
    const int m0 = blockIdx.y * 64;
    const int n0 = blockIdx.x * 64;
    const int lr = tid >> 2;
    const int lk = (tid & 3) << 2;
    const int tm = tid >> 4;
    const int tn = tid & 15;
    float acc[4][4] = {};

    const float* Ap = A + (size_t)(m0 + lr) * K + lk;
    const float* Bp = B + (size_t)(n0 + lr) * K + lk;

    for (int kk = 0; kk < K; kk += 16) {
        float4 av = *(const float4*)(Ap + kk);
        float4 bv = *(const float4*)(Bp + kk);
        As[lk + 0][lr] = av.x; As[lk + 1][lr] = av.y;
        As[lk + 2][lr] = av.z; As[lk + 3][lr] = av.w;
        Bs[lk + 0][lr] = bv.x; Bs[lk + 1][lr] = bv.y;
        Bs[lk + 2][lr] = bv.z; Bs[lk + 3][lr] = bv.w;
        __syncthreads();
#pragma unroll
        for (int k2 = 0; k2 < 16; ++k2) {
            float4 a4 = *(const float4*)&As[k2][tm * 4];
            float4 b4 = *(const float4*)&Bs[k2][tn * 4];
            float ar[4] = {a4.x, a4.y, a4.z, a4.w};
            float br[4] = {b4.x, b4.y, b4.z, b4.w};
#pragma unroll
            for (int i = 0; i < 4; ++i)
#pragma unroll
                for (int j = 0; j < 4; ++j) acc[i][j] += ar[i] * br[j];
        }
        __syncthreads();
    }

#pragma unroll
    for (int i = 0; i < 4; ++i) {
        int m = m0 + tm * 4 + i;
        int n = n0 + tn * 4;
        float4 v = {acc[i][0], acc[i][1], acc[i][2], acc[i][3]};
        *(float4*)&C[(size_t)m * N + n] = v;
    }
}

// ---------------------------------------------------------------------------
// b/a projections: beta = sigmoid(b); lg = -exp(A_log)*softplus(a+dt_bias)
// (log-gamma stored, NOT gamma — chunk kernel needs exp(c_t - c_s) safely)
// ---------------------------------------------------------------------------
__global__ __launch_bounds__(64) void proj_ba(const float* __restrict__ H,
                                              const float* __restrict__ Wb,
                                              const float* __restrict__ Wa,
                                              const float* __restrict__ dtb,
                                              const float* __restrict__ Alog,
                                              float* __restrict__ betab,
                                              float* __restrict__ lgb) {
    const int tok = blockIdx.x;
    const int lane = threadIdx.x;
    if (lane >= 32) return;
    const float* w = (lane < 16) ? (Wb + (size_t)lane * HIDDEN)
                                 : (Wa + (size_t)(lane - 16) * HIDDEN);
    const float4* wp = (const float4*)w;
    const float4* hp = (const float4*)(H + (size_t)tok * HIDDEN);
    float s = 0.f;
    for (int i = 0; i < HIDDEN / 4; ++i) {
        float4 a = hp[i], c = wp[i];
        s += a.x * c.x + a.y * c.y + a.z * c.z + a.w * c.w;
    }
    if (lane < 16) {
        betab[tok * HV + lane] = 1.f / (1.f + expf(-s));
    } else {
        int hh = lane - 16;
        float x = s + dtb[hh];
        float sp = (x > 20.f) ? x : log1pf(expf(x));
        lgb[tok * HV + hh] = -expf(Alog[hh]) * sp;
    }
}

// ---------------------------------------------------------------------------
// Causal depthwise conv(K=4) + silu, per-head L2 norm of q,k. Block per token.
// ---------------------------------------------------------------------------
__global__ __launch_bounds__(256) void conv_norm(const float* __restrict__ mixed,
                                                 const float* __restrict__ cw,
                                                 const int* __restrict__ cu,
                                                 float* __restrict__ qb,
                                                 float* __restrict__ kb,
                                                 float* __restrict__ vb) {
    const int tok = blockIdx.x;
    const int tid = threadIdx.x;
    __shared__ float yl[CONV_DIM];
    __shared__ float scale[16];

    int b = 0;
    for (int i = 1; i < NSEQ; ++i)
        if (tok >= cu[i]) b = i;
    const int pos = tok - cu[b];

    for (int c = tid; c < CONV_DIM; c += 256) {
        float acc = 0.f;
#pragma unroll
        for (int j = 0; j < KSZ; ++j) {
            int off = j - (KSZ - 1);
            float x = (pos + off >= 0) ? mixed[(size_t)(tok + off) * CONV_DIM + c] : 0.f;
            acc += cw[c * KSZ + j] * x;
        }
        yl[c] = acc / (1.f + expf(-acc));  // silu
    }
    __syncthreads();

    if (tid < 16) {
        float p = 0.f;
        for (int u = 0; u < 64; ++u) {
            float v = yl[tid * 64 + u];
            p += v * v;
        }
        scale[tid] = rsqrtf(p + 1e-6f);
    }
    __syncthreads();

    for (int c = tid; c < CONV_DIM; c += 256) {
        float y = yl[c];
        if (c < KEY_DIM) {
            qb[(size_t)tok * KEY_DIM + c] = y * scale[c >> 6] * 0.125f;  // * DK^-0.5
        } else if (c < 2 * KEY_DIM) {
            kb[(size_t)tok * KEY_DIM + (c - KEY_DIM)] = y * scale[c >> 6];
        } else {
            vb[(size_t)tok * VAL_DIM + (c - 2 * KEY_DIM)] = y;
        }
    }
}

// ---------------------------------------------------------------------------
// Chunked (WY) gated delta rule. One block (256 thr) per (seq, value-head).
// Chunk C=64. Within chunk (0-based t, inclusive prefix c_t = sum lg):
//   A[t][s] = beta_t e^{c_t-c_s} (k_t.k_s)  (s<t, else 0)
//   B[t]    = beta_t (v_t - e^{c_t} k_t^T S0)
//   U = (I+A)^{-1} B    (forward substitution, lane=dv, U in registers)
//   O[t]    = e^{c_t} q_t^T S0 + sum_{s<=t} e^{c_t-c_s}(q_t.k_s) U[s]
//   S0 <- e^{c_63} S0 + sum_s e^{c_63-c_s} k_s U_s^T
// Padding (tau>=t1): k=q=v=0, beta=0, lg=0 -> exactly a no-op.
// ---------------------------------------------------------------------------
__global__ __launch_bounds__(256) void delta_chunk(const float* __restrict__ qb,
                                                   const float* __restrict__ kb,
                                                   const float* __restrict__ vb,
                                                   const float* __restrict__ lgb,
                                                   const float* __restrict__ betab,
                                                   const int* __restrict__ cu,
                                                   float* __restrict__ ob) {
    const int bh = blockIdx.x;
    const int b = bh >> 4, h = bh & 15, hk = h >> 1;
    const int tid = threadIdx.x;
    const int lane = tid & 63;
    const int w = tid >> 6;
    const int tm = tid >> 4;   // 0..15 (t-block of 4)
    const int tn = tid & 15;   // 0..15 (s/dv-block of 4)

    __shared__ float KlT[64 * SK];   // [dk][t]
    __shared__ float QlT[64 * SK];   // [dk][t]
    __shared__ float Vl[64 * 64];    // [t][dv] -> becomes B in place
    __shared__ float S0l[64 * SS];   // [dk][dv]
    __shared__ float Am[64 * SS];    // A, then P
    __shared__ float G0[64 * SS];    // KS0, then QS0
    __shared__ float cl[64], el[64], bl[64], lgl[64], dscl[64];

    for (int i = tid; i < 64 * SS; i += 256) S0l[i] = 0.f;

    const int t0 = cu[b], t1 = cu[b + 1];

    for (int base = t0; base < t1; base += 64) {
        __syncthreads();  // protect LDS (incl. first-iter S0 init)

        // ---- load K,Q (transposed), V, lg, beta; zero-pad past t1 ----
        {
            const int tt = tid >> 2;
            const int d0 = (tid & 3) << 4;
            const int tau = base + tt;
            const bool valid = tau < t1;
            const float4 z4 = {0.f, 0.f, 0.f, 0.f};
#pragma unroll
            for (int u4 = 0; u4 < 4; ++u4) {
                const int d = d0 + u4 * 4;
                float4 kv = valid ? *(const float4*)&kb[(size_t)tau * KEY_DIM + hk * 64 + d] : z4;
                float4 qv = valid ? *(const float4*)&qb[(size_t)tau * KEY_DIM + hk * 64 + d] : z4;
                float4 vv = valid ? *(const float4*)&vb[(size_t)tau * VAL_DIM + h * 64 + d] : z4;
                KlT[(d + 0) * SK + tt] = kv.x; KlT[(d + 1) * SK + tt] = kv.y;
                KlT[(d + 2) * SK + tt] = kv.z; KlT[(d + 3) * SK + tt] = kv.w;
                QlT[(d + 0) * SK + tt] = qv.x; QlT[(d + 1) * SK + tt] = qv.y;
                QlT[(d + 2) * SK + tt] = qv.z; QlT[(d + 3) * SK + tt] = qv.w;
                *(float4*)&Vl[tt * 64 + d] = vv;
            }
            if (tid < 64) {
                const int ta = base + tid;
                const bool v2 = ta < t1;
                lgl[tid] = v2 ? lgb[ta * HV + h] : 0.f;
                bl[tid]  = v2 ? betab[ta * HV + h] : 0.f;
            }
        }
        __syncthreads();

        // ---- wave 0: inclusive scan of lg -> c, e=exp(c), dsc=exp(c63-c) ----
        if (w == 0) {
            float x = lgl[lane];
#pragma unroll
            for (int off = 1; off < 64; off <<= 1) {
                float y = __shfl_up(x, off);
                if (lane >= off) x += y;
            }
            cl[lane] = x;
            el[lane] = expf(x);
            float c63 = __shfl(x, 63);
            dscl[lane] = expf(c63 - x);
        }
        __syncthreads();

        // ---- A-gram (k.k) + KS0 matmul ----
        {
            float a[4][4] = {};
            float g[4][4] = {};
            for (int d = 0; d < 64; ++d) {
                float4 kt = *(const float4*)&KlT[d * SK + tm * 4];
                float4 ks = *(const float4*)&KlT[d * SK + tn * 4];
                float4 s0 = *(const float4*)&S0l[d * SS + tn * 4];
                float ktr[4] = {kt.x, kt.y, kt.z, kt.w};
                float ksr[4] = {ks.x, ks.y, ks.z, ks.w};
                float s0r[4] = {s0.x, s0.y, s0.z, s0.w};
#pragma unroll
                for (int i = 0; i < 4; ++i)
#pragma unroll
                    for (int j = 0; j < 4; ++j) {
                        a[i][j] += ktr[i] * ksr[j];
                        g[i][j] += ktr[i] * s0r[j];
                    }
            }
#pragma unroll
            for (int i = 0; i < 4; ++i) {
                const int t = tm * 4 + i;
#pragma unroll
                for (int j = 0; j < 4; ++j) {
                    const int s = tn * 4 + j;
                    Am[t * SS + s] = (s < t) ? bl[t] * expf(cl[t] - cl[s]) * a[i][j] : 0.f;
                    G0[t * SS + s] = g[i][j];   // KS0 tile (s == dv here)
                }
            }
        }
        __syncthreads();

        // ---- B in place on Vl: B[t][dv] = beta_t*(V - e_t*KS0) ----
        {
#pragma unroll
            for (int i = 0; i < 16; ++i) {
                const int t = w * 16 + i;
                const float bt = bl[t], et = el[t];
                Vl[t * 64 + lane] = bt * (Vl[t * 64 + lane] - et * G0[t * SS + lane]);
            }
        }
        __syncthreads();

        // ---- forward substitution (all 4 waves redundant), U in registers ----
        float U[64];
#pragma unroll
        for (int t = 0; t < 64; ++t) U[t] = 0.f;
#pragma unroll
        for (int t = 0; t < 64; ++t) {
            float a0 = 0.f, a1 = 0.f, a2 = 0.f, a3 = 0.f;
#pragma unroll
            for (int s5 = 0; s5 <= (t >> 2); ++s5) {
                float4 ar = *(const float4*)&Am[t * SS + s5 * 4];
                a0 += ar.x * U[s5 * 4 + 0];
                a1 += ar.y * U[s5 * 4 + 1];
                a2 += ar.z * U[s5 * 4 + 2];
                a3 += ar.w * U[s5 * 4 + 3];
            }
            U[t] = Vl[t * 64 + lane] - ((a0 + a1) + (a2 + a3));
        }
        __syncthreads();  // everyone done reading Am/Vl

        // ---- P-gram (q.k, into Am) + QS0 (into G0) ----
        {
            float a[4][4] = {};
            float g[4][4] = {};
            for (int d = 0; d < 64; ++d) {
                float4 qt = *(const float4*)&QlT[d * SK + tm * 4];
                float4 ks = *(const float4*)&KlT[d * SK + tn * 4];
                float4 s0 = *(const float4*)&S0l[d * SS + tn * 4];
                float qtr[4] = {qt.x, qt.y, qt.z, qt.w};
                float ksr[4] = {ks.x, ks.y, ks.z, ks.w};
                float s0r[4] = {s0.x, s0.y, s0.z, s0.w};
#pragma unroll
                for (int i = 0; i < 4; ++i)
#pragma unroll
                    for (int j = 0; j < 4; ++j) {
                        a[i][j] += qtr[i] * ksr[j];
                        g[i][j] += qtr[i] * s0r[j];
                    }
            }
#pragma unroll
            for (int i = 0; i < 4; ++i) {
                const int t = tm * 4 + i;
#pragma unroll
                for (int j = 0; j < 4; ++j) {
                    const int s = tn * 4 + j;
                    Am[t * SS + s] = (s <= t) ? expf(cl[t] - cl[s]) * a[i][j] : 0.f;
                    G0[t * SS + s] = g[i][j];   // QS0 tile
                }
            }
        }
        __syncthreads();

        // ---- O output + state update ----
        {
            // O: wave w handles t rows [16w, 16w+16)
#pragma unroll
            for (int i = 0; i < 16; ++i) {
                const int t = w * 16 + i;
                float o0 = 0.f, o1 = 0.f, o2 = 0.f, o3 = 0.f;
#pragma unroll
                for (int s5 = 0; s5 < 16; ++s5) {
                    float4 pr = *(const float4*)&Am[t * SS + s5 * 4];
                    o0 += pr.x * U[s5 * 4 + 0];
                    o1 += pr.y * U[s5 * 4 + 1];
                    o2 += pr.z * U[s5 * 4 + 2];
                    o3 += pr.w * U[s5 * 4 + 3];
                }
                const int tau = base + t;
                if (tau < t1)
                    ob[(size_t)tau * VAL_DIM + h * 64 + lane] =
                        el[t] * G0[t * SS + lane] + ((o0 + o1) + (o2 + o3));
            }
            // scale U by dsc (U dead for O now)
#pragma unroll
            for (int s = 0; s < 64; ++s) U[s] *= dscl[s];
            const float e63v = el[63];
            // state: thread (w,lane) updates rows r=16w..16w+15, col lane
#pragma unroll
            for (int i = 0; i < 16; ++i) {
                const int r = w * 16 + i;
                float acc = e63v * S0l[r * SS + lane];
#pragma unroll
                for (int s5 = 0; s5 < 16; ++s5) {
                    float4 kr = *(const float4*)&KlT[r * SK + s5 * 4];
                    acc += kr.x * U[s5 * 4 + 0] + kr.y * U[s5 * 4 + 1]
                         + kr.z * U[s5 * 4 + 2] + kr.w * U[s5 * 4 + 3];
                }
                S0l[r * SS + lane] = acc;
            }
        }
    }
}

// ---------------------------------------------------------------------------
// Gated RMSNorm (in-place): o * rsqrt(mean(o^2)+eps) * nw * silu(z).
// ---------------------------------------------------------------------------
__global__ __launch_bounds__(256) void gated_norm(float* __restrict__ ob,
                                                  const float* __restrict__ zb,
                                                  const float* __restrict__ nw) {
    const int wid = blockIdx.x * 4 + (threadIdx.x >> 6);
    const int lane = threadIdx.x & 63;
    const int tok = wid >> 4, h = wid & 15;
    const size_t idx = (size_t)tok * VAL_DIM + h * 64 + lane;
    const float o = ob[idx];
    float ss = o * o;
#pragma unroll
    for (int m = 1; m < 64; m <<= 1) ss += __shfl_xor(ss, m);
    const float r = rsqrtf(ss * (1.f / 64.f) + 1e-6f);
    const float z = zb[idx];
    const float sz = z / (1.f + expf(-z));
    ob[idx] = o * r * nw[lane] * sz;
}

// ---------------------------------------------------------------------------
extern "C" void kernel_launch(void* const* d_in, const int* in_sizes, int n_in,
                              void* d_out, int out_size, void* d_ws, size_t ws_size,
                              hipStream_t stream) {
    const float* H    = (const float*)d_in[0];
    const float* Wqkv = (const float*)d_in[1];
    const float* Wz   = (const float*)d_in[2];
    const float* Wb   = (const float*)d_in[3];
    const float* Wa   = (const float*)d_in[4];
    const float* cwt  = (const float*)d_in[5];
    const float* dtb  = (const float*)d_in[6];
    const float* Alog = (const float*)d_in[7];
    const float* nw   = (const float*)d_in[8];
    const float* Wout = (const float*)d_in[9];
    const int*   cu   = (const int*)d_in[10];
    float* out = (float*)d_out;

    float* wsf = (float*)d_ws;
    float* mixed = wsf;                                  // gemm1 -> conv
    float* obuf  = wsf;                                  // alias of dead mixed
    float* qbuf  = wsf + (size_t)TOTAL * CONV_DIM;
    float* kbuf  = qbuf + (size_t)TOTAL * KEY_DIM;
    float* vbuf  = kbuf + (size_t)TOTAL * KEY_DIM;
    float* zbuf  = qbuf;                                 // alias of dead q+k
    float* lgbuf = vbuf + (size_t)TOTAL * VAL_DIM;       // log-gamma
    float* bbuf  = lgbuf + (size_t)TOTAL * HV;           // beta

    // 1) mixed = H @ W_qkv^T   (1536 x 2048)
    gemm_tn<<<dim3(CONV_DIM / 64, TOTAL / 64), 256, 0, stream>>>(
        H, Wqkv, mixed, TOTAL, CONV_DIM, HIDDEN);
    // 2) beta / log-gamma
    proj_ba<<<TOTAL, 64, 0, stream>>>(H, Wb, Wa, dtb, Alog, bbuf, lgbuf);
    // 3) conv + silu + l2 norm -> q,k,v
    conv_norm<<<TOTAL, 256, 0, stream>>>(mixed, cwt, cu, qbuf, kbuf, vbuf);
    // 4) chunked gated delta rule -> o (aliases dead mixed)
    delta_chunk<<<NSEQ * HV, 256, 0, stream>>>(qbuf, kbuf, vbuf, lgbuf, bbuf, cu, obuf);
    // 5) z = H @ W_z^T (aliases dead q+k)
    gemm_tn<<<dim3(VAL_DIM / 64, TOTAL / 64), 256, 0, stream>>>(
        H, Wz, zbuf, TOTAL, VAL_DIM, HIDDEN);
    // 6) gated RMSNorm in-place on o
    gated_norm<<<TOTAL * HV / 4, 256, 0, stream>>>(obuf, zbuf, nw);
    // 7) out = o @ W_out^T -> fp32 d_out
    gemm_tn<<<dim3(HIDDEN / 64, TOTAL / 64), 256, 0, stream>>>(
        obuf, Wout, out, TOTAL, HIDDEN, VAL_DIM);
}

// Round 7
// 679.344 us; speedup vs baseline: 3.0588x; 3.0588x over previous
//
#include <hip/hip_runtime.h>
#include <hip/hip_bf16.h>
#include <cstddef>

// Problem constants (fixed by setup_inputs)
#define TOTAL   1536
#define HIDDEN  1024
#define HK      8
#define HV      16
#define DK      64
#define DV      64
#define KSZ     4
#define KEY_DIM 512
#define VAL_DIM 1024
#define CONV_DIM 2048
#define NSEQ    4

// LDS strides (floats) for the chunk kernel
#define SK 68   // KlT/QlT row stride
#define SS 68   // S0l / Am / G0 stride

// ---------------------------------------------------------------------------
// GEMM: C[M,N] = A[M,K] @ B[N,K]^T, fp32. 64x64 tile, BK=16, 256 thr, 4x4 micro.
// ---------------------------------------------------------------------------
__global__ __launch_bounds__(256) void gemm_tn(const float* __restrict__ A,
                                               const float* __restrict__ B,
                                               float* __restrict__ C,
                                               int M, int N, int K) {
    __shared__ float As[16][68];
    __shared__ float Bs[16][68];
    const int tid = threadIdx.x;
    const int m0 = blockIdx.y * 64;
    const int n0 = blockIdx.x * 64;
    const int lr = tid >> 2;
    const int lk = (tid & 3) << 2;
    const int tm = tid >> 4;
    const int tn = tid & 15;
    float acc[4][4] = {};

    const float* Ap = A + (size_t)(m0 + lr) * K + lk;
    const float* Bp = B + (size_t)(n0 + lr) * K + lk;

    for (int kk = 0; kk < K; kk += 16) {
        float4 av = *(const float4*)(Ap + kk);
        float4 bv = *(const float4*)(Bp + kk);
        As[lk + 0][lr] = av.x; As[lk + 1][lr] = av.y;
        As[lk + 2][lr] = av.z; As[lk + 3][lr] = av.w;
        Bs[lk + 0][lr] = bv.x; Bs[lk + 1][lr] = bv.y;
        Bs[lk + 2][lr] = bv.z; Bs[lk + 3][lr] = bv.w;
        __syncthreads();
#pragma unroll
        for (int k2 = 0; k2 < 16; ++k2) {
            float4 a4 = *(const float4*)&As[k2][tm * 4];
            float4 b4 = *(const float4*)&Bs[k2][tn * 4];
            float ar[4] = {a4.x, a4.y, a4.z, a4.w};
            float br[4] = {b4.x, b4.y, b4.z, b4.w};
#pragma unroll
            for (int i = 0; i < 4; ++i)
#pragma unroll
                for (int j = 0; j < 4; ++j) acc[i][j] += ar[i] * br[j];
        }
        __syncthreads();
    }

#pragma unroll
    for (int i = 0; i < 4; ++i) {
        int m = m0 + tm * 4 + i;
        int n = n0 + tn * 4;
        float4 v = {acc[i][0], acc[i][1], acc[i][2], acc[i][3]};
        *(float4*)&C[(size_t)m * N + n] = v;
    }
}

// ---------------------------------------------------------------------------
// b/a projections: beta = sigmoid(b); lg = -exp(A_log)*softplus(a+dt_bias)
// ---------------------------------------------------------------------------
__global__ __launch_bounds__(64) void proj_ba(const float* __restrict__ H,
                                              const float* __restrict__ Wb,
                                              const float* __restrict__ Wa,
                                              const float* __restrict__ dtb,
                                              const float* __restrict__ Alog,
                                              float* __restrict__ betab,
                                              float* __restrict__ lgb) {
    const int tok = blockIdx.x;
    const int lane = threadIdx.x;
    if (lane >= 32) return;
    const float* w = (lane < 16) ? (Wb + (size_t)lane * HIDDEN)
                                 : (Wa + (size_t)(lane - 16) * HIDDEN);
    const float4* wp = (const float4*)w;
    const float4* hp = (const float4*)(H + (size_t)tok * HIDDEN);
    float s = 0.f;
    for (int i = 0; i < HIDDEN / 4; ++i) {
        float4 a = hp[i], c = wp[i];
        s += a.x * c.x + a.y * c.y + a.z * c.z + a.w * c.w;
    }
    if (lane < 16) {
        betab[tok * HV + lane] = 1.f / (1.f + expf(-s));
    } else {
        int hh = lane - 16;
        float x = s + dtb[hh];
        float sp = (x > 20.f) ? x : log1pf(expf(x));
        lgb[tok * HV + hh] = -expf(Alog[hh]) * sp;
    }
}

// ---------------------------------------------------------------------------
// Causal depthwise conv(K=4) + silu, per-head L2 norm of q,k. Block per token.
// ---------------------------------------------------------------------------
__global__ __launch_bounds__(256) void conv_norm(const float* __restrict__ mixed,
                                                 const float* __restrict__ cw,
                                                 const int* __restrict__ cu,
                                                 float* __restrict__ qb,
                                                 float* __restrict__ kb,
                                                 float* __restrict__ vb) {
    const int tok = blockIdx.x;
    const int tid = threadIdx.x;
    __shared__ float yl[CONV_DIM];
    __shared__ float scale[16];

    int b = 0;
    for (int i = 1; i < NSEQ; ++i)
        if (tok >= cu[i]) b = i;
    const int pos = tok - cu[b];

    for (int c = tid; c < CONV_DIM; c += 256) {
        float acc = 0.f;
#pragma unroll
        for (int j = 0; j < KSZ; ++j) {
            int off = j - (KSZ - 1);
            float x = (pos + off >= 0) ? mixed[(size_t)(tok + off) * CONV_DIM + c] : 0.f;
            acc += cw[c * KSZ + j] * x;
        }
        yl[c] = acc / (1.f + expf(-acc));  // silu
    }
    __syncthreads();

    if (tid < 16) {
        float p = 0.f;
        for (int u = 0; u < 64; ++u) {
            float v = yl[tid * 64 + u];
            p += v * v;
        }
        scale[tid] = rsqrtf(p + 1e-6f);
    }
    __syncthreads();

    for (int c = tid; c < CONV_DIM; c += 256) {
        float y = yl[c];
        if (c < KEY_DIM) {
            qb[(size_t)tok * KEY_DIM + c] = y * scale[c >> 6] * 0.125f;  // * DK^-0.5
        } else if (c < 2 * KEY_DIM) {
            kb[(size_t)tok * KEY_DIM + (c - KEY_DIM)] = y * scale[c >> 6];
        } else {
            vb[(size_t)tok * VAL_DIM + (c - 2 * KEY_DIM)] = y;
        }
    }
}

// ---------------------------------------------------------------------------
// Chunked (WY) gated delta rule. One block (256 thr) per (seq, value-head).
// U lives in LDS (in place over Vl); blocked forward substitution;
// O and state updates are 4x4-microtile LDS matmuls. No big register arrays.
// ---------------------------------------------------------------------------
__global__ __launch_bounds__(256) void delta_chunk(const float* __restrict__ qb,
                                                   const float* __restrict__ kb,
                                                   const float* __restrict__ vb,
                                                   const float* __restrict__ lgb,
                                                   const float* __restrict__ betab,
                                                   const int* __restrict__ cu,
                                                   float* __restrict__ ob) {
    const int bh = blockIdx.x;
    const int b = bh >> 4, h = bh & 15, hk = h >> 1;
    const int tid = threadIdx.x;
    const int lane = tid & 63;
    const int w = tid >> 6;
    const int tm = tid >> 4;   // 0..15 (row-block of 4)
    const int tn = tid & 15;   // 0..15 (col-block of 4)

    __shared__ float KlT[64 * SK];   // [dk][t]
    __shared__ float QlT[64 * SK];   // [dk][t]
    __shared__ float Vl[64 * 64];    // [t][dv]: V -> B -> U in place
    __shared__ float S0l[64 * SS];   // [dk][dv]
    __shared__ float Am[64 * SS];    // A, then P
    __shared__ float G0[64 * SS];    // KS0, then QS0
    __shared__ float cl[64], el[64], bl[64], lgl[64], dscl[64];

    for (int i = tid; i < 64 * SS; i += 256) S0l[i] = 0.f;

    const int t0 = cu[b], t1 = cu[b + 1];

    for (int base = t0; base < t1; base += 64) {
        __syncthreads();  // protect LDS (incl. first-iter S0 init)

        // ---- load K,Q (transposed), V, lg, beta; zero-pad past t1 ----
        {
            const int tt = tid >> 2;
            const int d0 = (tid & 3) << 4;
            const int tau = base + tt;
            const bool valid = tau < t1;
            const float4 z4 = {0.f, 0.f, 0.f, 0.f};
#pragma unroll
            for (int u4 = 0; u4 < 4; ++u4) {
                const int d = d0 + u4 * 4;
                float4 kv = valid ? *(const float4*)&kb[(size_t)tau * KEY_DIM + hk * 64 + d] : z4;
                float4 qv = valid ? *(const float4*)&qb[(size_t)tau * KEY_DIM + hk * 64 + d] : z4;
                float4 vv = valid ? *(const float4*)&vb[(size_t)tau * VAL_DIM + h * 64 + d] : z4;
                KlT[(d + 0) * SK + tt] = kv.x; KlT[(d + 1) * SK + tt] = kv.y;
                KlT[(d + 2) * SK + tt] = kv.z; KlT[(d + 3) * SK + tt] = kv.w;
                QlT[(d + 0) * SK + tt] = qv.x; QlT[(d + 1) * SK + tt] = qv.y;
                QlT[(d + 2) * SK + tt] = qv.z; QlT[(d + 3) * SK + tt] = qv.w;
                *(float4*)&Vl[tt * 64 + d] = vv;
            }
            if (tid < 64) {
                const int ta = base + tid;
                const bool v2 = ta < t1;
                lgl[tid] = v2 ? lgb[ta * HV + h] : 0.f;
                bl[tid]  = v2 ? betab[ta * HV + h] : 0.f;
            }
        }
        __syncthreads();

        // ---- wave 0: inclusive scan of lg -> c, e=exp(c), dsc=exp(c63-c) ----
        if (w == 0) {
            float x = lgl[lane];
#pragma unroll
            for (int off = 1; off < 64; off <<= 1) {
                float y = __shfl_up(x, off);
                if (lane >= off) x += y;
            }
            cl[lane] = x;
            el[lane] = expf(x);
            float c63 = __shfl(x, 63);
            dscl[lane] = expf(c63 - x);
        }
        __syncthreads();

        // ---- A-gram (k.k) + KS0 matmul ----
        {
            float a[4][4] = {};
            float g[4][4] = {};
            for (int d = 0; d < 64; ++d) {
                float4 kt = *(const float4*)&KlT[d * SK + tm * 4];
                float4 ks = *(const float4*)&KlT[d * SK + tn * 4];
                float4 s0 = *(const float4*)&S0l[d * SS + tn * 4];
                float ktr[4] = {kt.x, kt.y, kt.z, kt.w};
                float ksr[4] = {ks.x, ks.y, ks.z, ks.w};
                float s0r[4] = {s0.x, s0.y, s0.z, s0.w};
#pragma unroll
                for (int i = 0; i < 4; ++i)
#pragma unroll
                    for (int j = 0; j < 4; ++j) {
                        a[i][j] += ktr[i] * ksr[j];
                        g[i][j] += ktr[i] * s0r[j];
                    }
            }
#pragma unroll
            for (int i = 0; i < 4; ++i) {
                const int t = tm * 4 + i;
#pragma unroll
                for (int j = 0; j < 4; ++j) {
                    const int s = tn * 4 + j;
                    Am[t * SS + s] = (s < t) ? bl[t] * expf(cl[t] - cl[s]) * a[i][j] : 0.f;
                    G0[t * SS + s] = g[i][j];   // KS0 tile (s == dv here)
                }
            }
        }
        __syncthreads();

        // ---- B in place on Vl: B[t][dv] = beta_t*(V - e_t*KS0) ----
#pragma unroll
        for (int i = 0; i < 16; ++i) {
            const int t = w * 16 + i;
            Vl[t * 64 + lane] = bl[t] * (Vl[t * 64 + lane] - el[t] * G0[t * SS + lane]);
        }
        __syncthreads();

        // ---- blocked forward substitution: U in place on Vl ----
#pragma unroll
        for (int ib = 0; ib < 4; ++ib) {
            if (w == 0) {
                // serial 16-step triangular solve of diagonal block (lane = dv)
                float ur[16];
#pragma unroll
                for (int i = 0; i < 16; ++i) {
                    const int t = ib * 16 + i;
                    float acc = Vl[t * 64 + lane];
#pragma unroll
                    for (int s = 0; s < 16; ++s)
                        if (s < i) acc -= Am[t * SS + ib * 16 + s] * ur[s];
                    ur[i] = acc;
                    Vl[t * 64 + lane] = acc;
                }
            }
            __syncthreads();
            if (ib < 3) {
                // rank-16 update of remaining rows, distributed across waves
                float us[16];
#pragma unroll
                for (int s = 0; s < 16; ++s) us[s] = Vl[(ib * 16 + s) * 64 + lane];
                for (int r = (ib + 1) * 16 + w; r < 64; r += 4) {
                    float acc = Vl[r * 64 + lane];
#pragma unroll
                    for (int s = 0; s < 16; ++s)
                        acc -= Am[r * SS + ib * 16 + s] * us[s];
                    Vl[r * 64 + lane] = acc;
                }
                __syncthreads();
            }
        }

        // ---- P-gram (q.k, into Am) + QS0 (into G0) ----
        {
            float a[4][4] = {};
            float g[4][4] = {};
            for (int d = 0; d < 64; ++d) {
                float4 qt = *(const float4*)&QlT[d * SK + tm * 4];
                float4 ks = *(const float4*)&KlT[d * SK + tn * 4];
                float4 s0 = *(const float4*)&S0l[d * SS + tn * 4];
                float qtr[4] = {qt.x, qt.y, qt.z, qt.w};
                float ksr[4] = {ks.x, ks.y, ks.z, ks.w};
                float s0r[4] = {s0.x, s0.y, s0.z, s0.w};
#pragma unroll
                for (int i = 0; i < 4; ++i)
#pragma unroll
                    for (int j = 0; j < 4; ++j) {
                        a[i][j] += qtr[i] * ksr[j];
                        g[i][j] += qtr[i] * s0r[j];
                    }
            }
#pragma unroll
            for (int i = 0; i < 4; ++i) {
                const int t = tm * 4 + i;
#pragma unroll
                for (int j = 0; j < 4; ++j) {
                    const int s = tn * 4 + j;
                    Am[t * SS + s] = (s <= t) ? expf(cl[t] - cl[s]) * a[i][j] : 0.f;
                    G0[t * SS + s] = g[i][j];   // QS0 tile
                }
            }
        }
        __syncthreads();

        // ---- O = el*QS0 + P@U  (4x4 microtile matmul over s) ----
        {
            float acc[4][4];
#pragma unroll
            for (int i = 0; i < 4; ++i) {
                const int t = tm * 4 + i;
                float4 g4 = *(const float4*)&G0[t * SS + tn * 4];
                acc[i][0] = el[t] * g4.x; acc[i][1] = el[t] * g4.y;
                acc[i][2] = el[t] * g4.z; acc[i][3] = el[t] * g4.w;
            }
            for (int s4 = 0; s4 < 16; ++s4) {
                float4 u0 = *(const float4*)&Vl[(s4 * 4 + 0) * 64 + tn * 4];
                float4 u1 = *(const float4*)&Vl[(s4 * 4 + 1) * 64 + tn * 4];
                float4 u2 = *(const float4*)&Vl[(s4 * 4 + 2) * 64 + tn * 4];
                float4 u3 = *(const float4*)&Vl[(s4 * 4 + 3) * 64 + tn * 4];
#pragma unroll
                for (int i = 0; i < 4; ++i) {
                    const int t = tm * 4 + i;
                    float4 p4 = *(const float4*)&Am[t * SS + s4 * 4];
                    acc[i][0] += p4.x * u0.x + p4.y * u1.x + p4.z * u2.x + p4.w * u3.x;
                    acc[i][1] += p4.x * u0.y + p4.y * u1.y + p4.z * u2.y + p4.w * u3.y;
                    acc[i][2] += p4.x * u0.z + p4.y * u1.z + p4.z * u2.z + p4.w * u3.z;
                    acc[i][3] += p4.x * u0.w + p4.y * u1.w + p4.z * u2.w + p4.w * u3.w;
                }
            }
#pragma unroll
            for (int i = 0; i < 4; ++i) {
                const int tau = base + tm * 4 + i;
                if (tau < t1) {
                    float4 v = {acc[i][0], acc[i][1], acc[i][2], acc[i][3]};
                    *(float4*)&ob[(size_t)tau * VAL_DIM + h * 64 + tn * 4] = v;
                }
            }
        }

        // ---- S0 <- e63*S0 + K^T diag(dsc) U  (4x4 microtile matmul) ----
        {
            const float e63v = el[63];
            float acc[4][4];
#pragma unroll
            for (int i = 0; i < 4; ++i) {
                const int r = tm * 4 + i;
                float4 s4v = *(const float4*)&S0l[r * SS + tn * 4];
                acc[i][0] = e63v * s4v.x; acc[i][1] = e63v * s4v.y;
                acc[i][2] = e63v * s4v.z; acc[i][3] = e63v * s4v.w;
            }
            for (int s4 = 0; s4 < 16; ++s4) {
                float4 d4 = *(const float4*)&dscl[s4 * 4];
                float4 u0 = *(const float4*)&Vl[(s4 * 4 + 0) * 64 + tn * 4];
                float4 u1 = *(const float4*)&Vl[(s4 * 4 + 1) * 64 + tn * 4];
                float4 u2 = *(const float4*)&Vl[(s4 * 4 + 2) * 64 + tn * 4];
                float4 u3 = *(const float4*)&Vl[(s4 * 4 + 3) * 64 + tn * 4];
                u0.x *= d4.x; u0.y *= d4.x; u0.z *= d4.x; u0.w *= d4.x;
                u1.x *= d4.y; u1.y *= d4.y; u1.z *= d4.y; u1.w *= d4.y;
                u2.x *= d4.z; u2.y *= d4.z; u2.z *= d4.z; u2.w *= d4.z;
                u3.x *= d4.w; u3.y *= d4.w; u3.z *= d4.w; u3.w *= d4.w;
#pragma unroll
                for (int i = 0; i < 4; ++i) {
                    const int r = tm * 4 + i;
                    float4 k4 = *(const float4*)&KlT[r * SK + s4 * 4];
                    acc[i][0] += k4.x * u0.x + k4.y * u1.x + k4.z * u2.x + k4.w * u3.x;
                    acc[i][1] += k4.x * u0.y + k4.y * u1.y + k4.z * u2.y + k4.w * u3.y;
                    acc[i][2] += k4.x * u0.z + k4.y * u1.z + k4.z * u2.z + k4.w * u3.z;
                    acc[i][3] += k4.x * u0.w + k4.y * u1.w + k4.z * u2.w + k4.w * u3.w;
                }
            }
            __syncthreads();  // all reads of old S0l done before overwrite
#pragma unroll
            for (int i = 0; i < 4; ++i) {
                const int r = tm * 4 + i;
                float4 v = {acc[i][0], acc[i][1], acc[i][2], acc[i][3]};
                *(float4*)&S0l[r * SS + tn * 4] = v;
            }
        }
    }
}

// ---------------------------------------------------------------------------
// Gated RMSNorm (in-place): o * rsqrt(mean(o^2)+eps) * nw * silu(z).
// ---------------------------------------------------------------------------
__global__ __launch_bounds__(256) void gated_norm(float* __restrict__ ob,
                                                  const float* __restrict__ zb,
                                                  const float* __restrict__ nw) {
    const int wid = blockIdx.x * 4 + (threadIdx.x >> 6);
    const int lane = threadIdx.x & 63;
    const int tok = wid >> 4, h = wid & 15;
    const size_t idx = (size_t)tok * VAL_DIM + h * 64 + lane;
    const float o = ob[idx];
    float ss = o * o;
#pragma unroll
    for (int m = 1; m < 64; m <<= 1) ss += __shfl_xor(ss, m);
    const float r = rsqrtf(ss * (1.f / 64.f) + 1e-6f);
    const float z = zb[idx];
    const float sz = z / (1.f + expf(-z));
    ob[idx] = o * r * nw[lane] * sz;
}

// ---------------------------------------------------------------------------
extern "C" void kernel_launch(void* const* d_in, const int* in_sizes, int n_in,
                              void* d_out, int out_size, void* d_ws, size_t ws_size,
                              hipStream_t stream) {
    const float* H    = (const float*)d_in[0];
    const float* Wqkv = (const float*)d_in[1];
    const float* Wz   = (const float*)d_in[2];
    const float* Wb   = (const float*)d_in[3];
    const float* Wa   = (const float*)d_in[4];
    const float* cwt  = (const float*)d_in[5];
    const float* dtb  = (const float*)d_in[6];
    const float* Alog = (const float*)d_in[7];
    const float* nw   = (const float*)d_in[8];
    const float* Wout = (const float*)d_in[9];
    const int*   cu   = (const int*)d_in[10];
    float* out = (float*)d_out;

    float* wsf = (float*)d_ws;
    float* mixed = wsf;                                  // gemm1 -> conv
    float* obuf  = wsf;                                  // alias of dead mixed
    float* qbuf  = wsf + (size_t)TOTAL * CONV_DIM;
    float* kbuf  = qbuf + (size_t)TOTAL * KEY_DIM;
    float* vbuf  = kbuf + (size_t)TOTAL * KEY_DIM;
    float* zbuf  = qbuf;                                 // alias of dead q+k
    float* lgbuf = vbuf + (size_t)TOTAL * VAL_DIM;       // log-gamma
    float* bbuf  = lgbuf + (size_t)TOTAL * HV;           // beta

    // 1) mixed = H @ W_qkv^T   (1536 x 2048)
    gemm_tn<<<dim3(CONV_DIM / 64, TOTAL / 64), 256, 0, stream>>>(
        H, Wqkv, mixed, TOTAL, CONV_DIM, HIDDEN);
    // 2) beta / log-gamma
    proj_ba<<<TOTAL, 64, 0, stream>>>(H, Wb, Wa, dtb, Alog, bbuf, lgbuf);
    // 3) conv + silu + l2 norm -> q,k,v
    conv_norm<<<TOTAL, 256, 0, stream>>>(mixed, cwt, cu, qbuf, kbuf, vbuf);
    // 4) chunked gated delta rule -> o (aliases dead mixed)
    delta_chunk<<<NSEQ * HV, 256, 0, stream>>>(qbuf, kbuf, vbuf, lgbuf, bbuf, cu, obuf);
    // 5) z = H @ W_z^T (aliases dead q+k)
    gemm_tn<<<dim3(VAL_DIM / 64, TOTAL / 64), 256, 0, stream>>>(
        H, Wz, zbuf, TOTAL, VAL_DIM, HIDDEN);
    // 6) gated RMSNorm in-place on o
    gated_norm<<<TOTAL * HV / 4, 256, 0, stream>>>(obuf, zbuf, nw);
    // 7) out = o @ W_out^T -> fp32 d_out
    gemm_tn<<<dim3(HIDDEN / 64, TOTAL / 64), 256, 0, stream>>>(
        obuf, Wout, out, TOTAL, HIDDEN, VAL_DIM);
}

// Round 8
// 369.121 us; speedup vs baseline: 5.6296x; 1.8404x over previous
//
#include <hip/hip_runtime.h>
#include <hip/hip_bf16.h>
#include <cstddef>

// Problem constants (fixed by setup_inputs)
#define TOTAL   1536
#define HIDDEN  1024
#define HK      8
#define HV      16
#define DK      64
#define DV      64
#define KSZ     4
#define KEY_DIM 512
#define VAL_DIM 1024
#define CONV_DIM 2048
#define NSEQ    4

typedef unsigned short bfu;  // bf16 bits
typedef __attribute__((ext_vector_type(8))) short bf16x8;
typedef __attribute__((ext_vector_type(4))) float f32x4;

__device__ __forceinline__ bfu f2b(float f) {  // RNE
    unsigned x = __float_as_uint(f);
    return (bfu)((x + 0x7FFFu + ((x >> 16) & 1u)) >> 16);
}

// ---------------------------------------------------------------------------
// fp32 -> bf16 pack (grid-stride over 4-element groups)
// ---------------------------------------------------------------------------
__global__ __launch_bounds__(256) void to_bf16(const float* __restrict__ src,
                                               bfu* __restrict__ dst, int n) {
    int idx = (blockIdx.x * 256 + threadIdx.x) * 4;
    if (idx < n) {
        float4 v = *(const float4*)(src + idx);
        ushort4 o;
        o.x = f2b(v.x); o.y = f2b(v.y); o.z = f2b(v.z); o.w = f2b(v.w);
        *(ushort4*)(dst + idx) = o;
    }
}

// ---------------------------------------------------------------------------
// MFMA GEMM: C[M,N] = A[M,K] @ B[N,K]^T.  A,B bf16, C fp32.
// 128x128 tile, BK=64, 256 threads (4 waves, 64x64 per wave),
// v_mfma_f32_16x16x32_bf16. Frag maps: A/B row=lane&15,k=(lane>>4)*8;
// C/D col=lane&15,row=(lane>>4)*4+reg  [m89/m91-verified].
// ---------------------------------------------------------------------------
#define LDK 72  // LDS row stride in bf16 (144B: 16B-aligned, 2-way banks max)
__global__ __launch_bounds__(256) void gemm_mfma(const bfu* __restrict__ A,
                                                 const bfu* __restrict__ B,
                                                 float* __restrict__ C,
                                                 int M, int N, int K) {
    __shared__ bfu As[128 * LDK];
    __shared__ bfu Bs[128 * LDK];
    const int tid = threadIdx.x;
    const int m0 = blockIdx.y * 128, n0 = blockIdx.x * 128;
    const int lane = tid & 63, w = tid >> 6;
    const int wm = (w >> 1) * 64, wn = (w & 1) * 64;
    const int fr = lane & 15;
    const int fk = (lane >> 4) * 8;
    const int sr = tid >> 1;            // staging row 0..127
    const int sc = (tid & 1) * 32;      // staging col 0/32

    f32x4 acc[4][4];
#pragma unroll
    for (int i = 0; i < 4; ++i)
#pragma unroll
        for (int j = 0; j < 4; ++j) acc[i][j] = (f32x4){0.f, 0.f, 0.f, 0.f};

    for (int kk = 0; kk < K; kk += 64) {
        const bfu* ga = A + (size_t)(m0 + sr) * K + kk + sc;
        const bfu* gb = B + (size_t)(n0 + sr) * K + kk + sc;
        uint4 a0 = *(const uint4*)(ga + 0);
        uint4 a1 = *(const uint4*)(ga + 8);
        uint4 a2 = *(const uint4*)(ga + 16);
        uint4 a3 = *(const uint4*)(ga + 24);
        uint4 b0 = *(const uint4*)(gb + 0);
        uint4 b1 = *(const uint4*)(gb + 8);
        uint4 b2 = *(const uint4*)(gb + 16);
        uint4 b3 = *(const uint4*)(gb + 24);
        __syncthreads();  // previous K-tile consumed
        *(uint4*)&As[sr * LDK + sc + 0]  = a0;
        *(uint4*)&As[sr * LDK + sc + 8]  = a1;
        *(uint4*)&As[sr * LDK + sc + 16] = a2;
        *(uint4*)&As[sr * LDK + sc + 24] = a3;
        *(uint4*)&Bs[sr * LDK + sc + 0]  = b0;
        *(uint4*)&Bs[sr * LDK + sc + 8]  = b1;
        *(uint4*)&Bs[sr * LDK + sc + 16] = b2;
        *(uint4*)&Bs[sr * LDK + sc + 24] = b3;
        __syncthreads();

#pragma unroll
        for (int k2 = 0; k2 < 64; k2 += 32) {
            bf16x8 af[4], bfr[4];
#pragma unroll
            for (int i = 0; i < 4; ++i)
                af[i] = *(const bf16x8*)&As[(wm + i * 16 + fr) * LDK + k2 + fk];
#pragma unroll
            for (int j = 0; j < 4; ++j)
                bfr[j] = *(const bf16x8*)&Bs[(wn + j * 16 + fr) * LDK + k2 + fk];
#pragma unroll
            for (int i = 0; i < 4; ++i)
#pragma unroll
                for (int j = 0; j < 4; ++j)
                    acc[i][j] = __builtin_amdgcn_mfma_f32_16x16x32_bf16(
                        af[i], bfr[j], acc[i][j], 0, 0, 0);
        }
    }

    const int er = (lane >> 4) * 4;
#pragma unroll
    for (int i = 0; i < 4; ++i)
#pragma unroll
        for (int j = 0; j < 4; ++j) {
            const int col = n0 + wn + j * 16 + fr;
#pragma unroll
            for (int r = 0; r < 4; ++r) {
                const int row = m0 + wm + i * 16 + er + r;
                C[(size_t)row * N + col] = acc[i][j][r];
            }
        }
}

// ---------------------------------------------------------------------------
// b/a projections: beta = sigmoid(b); lg = -exp(A_log)*softplus(a+dt_bias)
// ---------------------------------------------------------------------------
__global__ __launch_bounds__(64) void proj_ba(const float* __restrict__ H,
                                              const float* __restrict__ Wb,
                                              const float* __restrict__ Wa,
                                              const float* __restrict__ dtb,
                                              const float* __restrict__ Alog,
                                              float* __restrict__ betab,
                                              float* __restrict__ lgb) {
    const int tok = blockIdx.x;
    const int lane = threadIdx.x;
    if (lane >= 32) return;
    const float* w = (lane < 16) ? (Wb + (size_t)lane * HIDDEN)
                                 : (Wa + (size_t)(lane - 16) * HIDDEN);
    const float4* wp = (const float4*)w;
    const float4* hp = (const float4*)(H + (size_t)tok * HIDDEN);
    float s = 0.f;
    for (int i = 0; i < HIDDEN / 4; ++i) {
        float4 a = hp[i], c = wp[i];
        s += a.x * c.x + a.y * c.y + a.z * c.z + a.w * c.w;
    }
    if (lane < 16) {
        betab[tok * HV + lane] = 1.f / (1.f + expf(-s));
    } else {
        int hh = lane - 16;
        float x = s + dtb[hh];
        float sp = (x > 20.f) ? x : log1pf(expf(x));
        lgb[tok * HV + hh] = -expf(Alog[hh]) * sp;
    }
}

// ---------------------------------------------------------------------------
// Causal depthwise conv(K=4) + silu, per-head L2 norm of q,k. Block per token.
// ---------------------------------------------------------------------------
__global__ __launch_bounds__(256) void conv_norm(const float* __restrict__ mixed,
                                                 const float* __restrict__ cw,
                                                 const int* __restrict__ cu,
                                                 float* __restrict__ qb,
                                                 float* __restrict__ kb,
                                                 float* __restrict__ vb) {
    const int tok = blockIdx.x;
    const int tid = threadIdx.x;
    __shared__ float yl[CONV_DIM];
    __shared__ float scale[16];

    int b = 0;
    for (int i = 1; i < NSEQ; ++i)
        if (tok >= cu[i]) b = i;
    const int pos = tok - cu[b];

    for (int c = tid; c < CONV_DIM; c += 256) {
        float acc = 0.f;
#pragma unroll
        for (int j = 0; j < KSZ; ++j) {
            int off = j - (KSZ - 1);
            float x = (pos + off >= 0) ? mixed[(size_t)(tok + off) * CONV_DIM + c] : 0.f;
            acc += cw[c * KSZ + j] * x;
        }
        yl[c] = acc / (1.f + expf(-acc));  // silu
    }
    __syncthreads();

    if (tid < 16) {
        float p = 0.f;
        for (int u = 0; u < 64; ++u) {
            float v = yl[tid * 64 + u];
            p += v * v;
        }
        scale[tid] = rsqrtf(p + 1e-6f);
    }
    __syncthreads();

    for (int c = tid; c < CONV_DIM; c += 256) {
        float y = yl[c];
        if (c < KEY_DIM) {
            qb[(size_t)tok * KEY_DIM + c] = y * scale[c >> 6] * 0.125f;  // * DK^-0.5
        } else if (c < 2 * KEY_DIM) {
            kb[(size_t)tok * KEY_DIM + (c - KEY_DIM)] = y * scale[c >> 6];
        } else {
            vb[(size_t)tok * VAL_DIM + (c - 2 * KEY_DIM)] = y;
        }
    }
}

// ---------------------------------------------------------------------------
// Chunked (WY) gated delta rule, dv-split x4.
// Block = (seq, v-head, dv-slice of 16). 256 thr. Grams full 64x64
// (dv-invariant, recomputed per slice); all dv-matmuls are 64x16.
// ---------------------------------------------------------------------------
#define SK 68   // KlT/QlT/Am row stride (floats)
#define SV 20   // Vl/S0l/G0 row stride (floats)
__global__ __launch_bounds__(256) void delta_chunk(const float* __restrict__ qb,
                                                   const float* __restrict__ kb,
                                                   const float* __restrict__ vb,
                                                   const float* __restrict__ lgb,
                                                   const float* __restrict__ betab,
                                                   const int* __restrict__ cu,
                                                   float* __restrict__ ob) {
    const int bh = blockIdx.x;
    const int b = bh >> 6, h = (bh >> 2) & 15, ds = bh & 3;
    const int hk = h >> 1, dv0 = ds * 16;
    const int tid = threadIdx.x;
    const int lane = tid & 63;
    const int w = tid >> 6;
    const int tm = tid >> 4;   // 0..15 (row-block of 4)
    const int tn = tid & 15;   // 0..15 (dv col / col-block of 4)

    __shared__ float KlT[64 * SK];   // [dk][t]
    __shared__ float QlT[64 * SK];   // [dk][t]
    __shared__ float Am[64 * SK];    // A, then P (full 64x64)
    __shared__ float Vl[64 * SV];    // [t][dv16]: V -> B -> U
    __shared__ float S0l[64 * SV];   // [dk][dv16]
    __shared__ float G0[64 * SV];    // KS0, then QS0 [t][dv16]
    __shared__ float cl[64], el[64], bl[64], lgl[64], dscl[64];

    for (int i = tid; i < 64 * SV; i += 256) S0l[i] = 0.f;

    const int t0 = cu[b], t1 = cu[b + 1];

    for (int base = t0; base < t1; base += 64) {
        __syncthreads();  // protect LDS (incl. first-iter S0 init / prev state)

        // ---- load K,Q transposed (full), V slice, lg, beta; zero-pad ----
        {
            const int tt = tid >> 2;
            const int d0 = (tid & 3) << 4;
            const int tau = base + tt;
            const bool valid = tau < t1;
            const float4 z4 = {0.f, 0.f, 0.f, 0.f};
#pragma unroll
            for (int u4 = 0; u4 < 4; ++u4) {
                const int d = d0 + u4 * 4;
                float4 kv = valid ? *(const float4*)&kb[(size_t)tau * KEY_DIM + hk * 64 + d] : z4;
                float4 qv = valid ? *(const float4*)&qb[(size_t)tau * KEY_DIM + hk * 64 + d] : z4;
                KlT[(d + 0) * SK + tt] = kv.x; KlT[(d + 1) * SK + tt] = kv.y;
                KlT[(d + 2) * SK + tt] = kv.z; KlT[(d + 3) * SK + tt] = kv.w;
                QlT[(d + 0) * SK + tt] = qv.x; QlT[(d + 1) * SK + tt] = qv.y;
                QlT[(d + 2) * SK + tt] = qv.z; QlT[(d + 3) * SK + tt] = qv.w;
            }
            const int j0 = (tid & 3) << 2;
            float4 vv = valid ? *(const float4*)&vb[(size_t)tau * VAL_DIM + h * 64 + dv0 + j0] : z4;
            *(float4*)&Vl[tt * SV + j0] = vv;
            if (tid < 64) {
                const int ta = base + tid;
                const bool v2 = ta < t1;
                lgl[tid] = v2 ? lgb[ta * HV + h] : 0.f;
                bl[tid]  = v2 ? betab[ta * HV + h] : 0.f;
            }
        }
        __syncthreads();

        // ---- wave 0: inclusive scan of lg -> c, e=exp(c), dsc=exp(c63-c) ----
        if (w == 0) {
            float x = lgl[lane];
#pragma unroll
            for (int off = 1; off < 64; off <<= 1) {
                float y = __shfl_up(x, off);
                if (lane >= off) x += y;
            }
            cl[lane] = x;
            el[lane] = expf(x);
            float c63 = __shfl(x, 63);
            dscl[lane] = expf(c63 - x);
        }
        __syncthreads();

        // ---- A-gram (k.k, full) + KS0 (64x16), fused over d ----
        {
            float a[4][4] = {};
            float g[4] = {};
            for (int d = 0; d < 64; ++d) {
                float4 kt = *(const float4*)&KlT[d * SK + tm * 4];
                float4 ks = *(const float4*)&KlT[d * SK + tn * 4];
                float s0 = S0l[d * SV + tn];
                float ktr[4] = {kt.x, kt.y, kt.z, kt.w};
                float ksr[4] = {ks.x, ks.y, ks.z, ks.w};
#pragma unroll
                for (int i = 0; i < 4; ++i) {
#pragma unroll
                    for (int j = 0; j < 4; ++j) a[i][j] += ktr[i] * ksr[j];
                    g[i] += ktr[i] * s0;
                }
            }
#pragma unroll
            for (int i = 0; i < 4; ++i) {
                const int t = tm * 4 + i;
#pragma unroll
                for (int j = 0; j < 4; ++j) {
                    const int s = tn * 4 + j;
                    Am[t * SK + s] = (s < t) ? bl[t] * expf(cl[t] - cl[s]) * a[i][j] : 0.f;
                }
                G0[t * SV + tn] = g[i];
            }
        }
        __syncthreads();

        // ---- B in place on Vl: B[t][j] = beta_t*(V - e_t*KS0) ----
        {
            const int t = tid >> 2;
            const int j0 = (tid & 3) << 2;
            float4 vv = *(const float4*)&Vl[t * SV + j0];
            float4 g4 = *(const float4*)&G0[t * SV + j0];
            const float bt = bl[t], et = el[t];
            float4 r;
            r.x = bt * (vv.x - et * g4.x); r.y = bt * (vv.y - et * g4.y);
            r.z = bt * (vv.z - et * g4.z); r.w = bt * (vv.w - et * g4.w);
            *(float4*)&Vl[t * SV + j0] = r;
        }
        __syncthreads();

        // ---- blocked forward substitution: U in place on Vl ----
#pragma unroll
        for (int ib = 0; ib < 4; ++ib) {
            if (tid < 16) {
                // serial 16-step triangular solve of diagonal block (tid = dv)
                float ur[16];
#pragma unroll
                for (int i = 0; i < 16; ++i) {
                    const int t = ib * 16 + i;
                    float acc = Vl[t * SV + tid];
#pragma unroll
                    for (int s = 0; s < 16; ++s)
                        if (s < i) acc -= Am[t * SK + ib * 16 + s] * ur[s];
                    ur[i] = acc;
                    Vl[t * SV + tid] = acc;
                }
            }
            __syncthreads();
            if (ib < 3) {
                float us[16];
#pragma unroll
                for (int s = 0; s < 16; ++s) us[s] = Vl[(ib * 16 + s) * SV + tn];
                for (int r = (ib + 1) * 16 + tm; r < 64; r += 16) {
                    float acc = Vl[r * SV + tn];
#pragma unroll
                    for (int s = 0; s < 16; ++s)
                        acc -= Am[r * SK + ib * 16 + s] * us[s];
                    Vl[r * SV + tn] = acc;
                }
                __syncthreads();
            }
        }

        // ---- P-gram (q.k, full, into Am) + QS0 (into G0), fused ----
        {
            float a[4][4] = {};
            float g[4] = {};
            for (int d = 0; d < 64; ++d) {
                float4 qt = *(const float4*)&QlT[d * SK + tm * 4];
                float4 ks = *(const float4*)&KlT[d * SK + tn * 4];
                float s0 = S0l[d * SV + tn];
                float qtr[4] = {qt.x, qt.y, qt.z, qt.w};
                float ksr[4] = {ks.x, ks.y, ks.z, ks.w};
#pragma unroll
                for (int i = 0; i < 4; ++i) {
#pragma unroll
                    for (int j = 0; j < 4; ++j) a[i][j] += qtr[i] * ksr[j];
                    g[i] += qtr[i] * s0;
                }
            }
#pragma unroll
            for (int i = 0; i < 4; ++i) {
                const int t = tm * 4 + i;
#pragma unroll
                for (int j = 0; j < 4; ++j) {
                    const int s = tn * 4 + j;
                    Am[t * SK + s] = (s <= t) ? expf(cl[t] - cl[s]) * a[i][j] : 0.f;
                }
                G0[t * SV + tn] = g[i];
            }
        }
        __syncthreads();

        // ---- O[t][j] = el*QS0 + P@U  (t-rows tm*4.., col tn) ----
        {
            float acc[4];
#pragma unroll
            for (int i = 0; i < 4; ++i) {
                const int t = tm * 4 + i;
                acc[i] = el[t] * G0[t * SV + tn];
            }
            for (int s4 = 0; s4 < 16; ++s4) {
                float u0 = Vl[(s4 * 4 + 0) * SV + tn];
                float u1 = Vl[(s4 * 4 + 1) * SV + tn];
                float u2 = Vl[(s4 * 4 + 2) * SV + tn];
                float u3 = Vl[(s4 * 4 + 3) * SV + tn];
#pragma unroll
                for (int i = 0; i < 4; ++i) {
                    const int t = tm * 4 + i;
                    float4 p4 = *(const float4*)&Am[t * SK + s4 * 4];
                    acc[i] += p4.x * u0 + p4.y * u1 + p4.z * u2 + p4.w * u3;
                }
            }
#pragma unroll
            for (int i = 0; i < 4; ++i) {
                const int tau = base + tm * 4 + i;
                if (tau < t1)
                    ob[(size_t)tau * VAL_DIM + h * 64 + dv0 + tn] = acc[i];
            }
        }

        // ---- S0 <- e63*S0 + K^T diag(dsc) U  (dk-rows tm*4.., col tn) ----
        {
            const float e63v = el[63];
            float acc[4];
#pragma unroll
            for (int i = 0; i < 4; ++i)
                acc[i] = e63v * S0l[(tm * 4 + i) * SV + tn];
            for (int s4 = 0; s4 < 16; ++s4) {
                float4 d4 = *(const float4*)&dscl[s4 * 4];
                float u0 = Vl[(s4 * 4 + 0) * SV + tn] * d4.x;
                float u1 = Vl[(s4 * 4 + 1) * SV + tn] * d4.y;
                float u2 = Vl[(s4 * 4 + 2) * SV + tn] * d4.z;
                float u3 = Vl[(s4 * 4 + 3) * SV + tn] * d4.w;
#pragma unroll
                for (int i = 0; i < 4; ++i) {
                    float4 k4 = *(const float4*)&KlT[(tm * 4 + i) * SK + s4 * 4];
                    acc[i] += k4.x * u0 + k4.y * u1 + k4.z * u2 + k4.w * u3;
                }
            }
            __syncthreads();  // all reads of old S0l done
#pragma unroll
            for (int i = 0; i < 4; ++i)
                S0l[(tm * 4 + i) * SV + tn] = acc[i];
        }
    }
}

// ---------------------------------------------------------------------------
// Gated RMSNorm: out_bf16 = o * rsqrt(mean(o^2)+eps) * nw * silu(z).
// ---------------------------------------------------------------------------
__global__ __launch_bounds__(256) void gated_norm(const float* __restrict__ ob,
                                                  const float* __restrict__ zb,
                                                  const float* __restrict__ nw,
                                                  bfu* __restrict__ obf) {
    const int wid = blockIdx.x * 4 + (threadIdx.x >> 6);
    const int lane = threadIdx.x & 63;
    const int tok = wid >> 4, h = wid & 15;
    const size_t idx = (size_t)tok * VAL_DIM + h * 64 + lane;
    const float o = ob[idx];
    float ss = o * o;
#pragma unroll
    for (int m = 1; m < 64; m <<= 1) ss += __shfl_xor(ss, m);
    const float r = rsqrtf(ss * (1.f / 64.f) + 1e-6f);
    const float z = zb[idx];
    const float sz = z / (1.f + expf(-z));
    obf[idx] = f2b(o * r * nw[lane] * sz);
}

// ---------------------------------------------------------------------------
extern "C" void kernel_launch(void* const* d_in, const int* in_sizes, int n_in,
                              void* d_out, int out_size, void* d_ws, size_t ws_size,
                              hipStream_t stream) {
    const float* H    = (const float*)d_in[0];
    const float* Wqkv = (const float*)d_in[1];
    const float* Wz   = (const float*)d_in[2];
    const float* Wb   = (const float*)d_in[3];
    const float* Wa   = (const float*)d_in[4];
    const float* cwt  = (const float*)d_in[5];
    const float* dtb  = (const float*)d_in[6];
    const float* Alog = (const float*)d_in[7];
    const float* nw   = (const float*)d_in[8];
    const float* Wout = (const float*)d_in[9];
    const int*   cu   = (const int*)d_in[10];
    float* out = (float*)d_out;

    // --- Workspace (~36.9 MB; ws_size >= 44.8 MB inferred R1-R3) ---
    float* wsf = (float*)d_ws;
    float* mixed = wsf;                                   // 3,145,728 f
    float* obuf  = wsf;                                   // alias (first 1,572,864 f)
    bfu*   obf   = (bfu*)(wsf + (size_t)TOTAL * VAL_DIM); // alias (next 786,432 f as bf16)
    float* qbuf  = wsf + (size_t)TOTAL * CONV_DIM;
    float* kbuf  = qbuf + (size_t)TOTAL * KEY_DIM;
    float* vbuf  = kbuf + (size_t)TOTAL * KEY_DIM;
    float* zbuf  = qbuf;                                  // alias of dead q+k
    float* lgbuf = vbuf + (size_t)TOTAL * VAL_DIM;
    float* bbuf  = lgbuf + (size_t)TOTAL * HV;
    bfu* Hb    = (bfu*)(bbuf + (size_t)TOTAL * HV);       // 1,572,864 bfu
    bfu* Wqkvb = Hb + (size_t)TOTAL * HIDDEN;             // 2,097,152 bfu
    bfu* Wzb   = Wqkvb + (size_t)CONV_DIM * HIDDEN;       // 1,048,576 bfu
    bfu* Woutb = Wzb + (size_t)VAL_DIM * HIDDEN;          // 1,048,576 bfu

    // 0) bf16 conversions
    to_bf16<<<(TOTAL * HIDDEN) / 1024, 256, 0, stream>>>(H, Hb, TOTAL * HIDDEN);
    to_bf16<<<(CONV_DIM * HIDDEN) / 1024, 256, 0, stream>>>(Wqkv, Wqkvb, CONV_DIM * HIDDEN);
    to_bf16<<<(VAL_DIM * HIDDEN) / 1024, 256, 0, stream>>>(Wz, Wzb, VAL_DIM * HIDDEN);
    to_bf16<<<(HIDDEN * VAL_DIM) / 1024, 256, 0, stream>>>(Wout, Woutb, HIDDEN * VAL_DIM);

    // 1) mixed = H @ W_qkv^T   (1536 x 2048) MFMA
    gemm_mfma<<<dim3(CONV_DIM / 128, TOTAL / 128), 256, 0, stream>>>(
        Hb, Wqkvb, mixed, TOTAL, CONV_DIM, HIDDEN);
    // 2) beta / log-gamma (fp32 inputs)
    proj_ba<<<TOTAL, 64, 0, stream>>>(H, Wb, Wa, dtb, Alog, bbuf, lgbuf);
    // 3) conv + silu + l2 norm -> q,k,v
    conv_norm<<<TOTAL, 256, 0, stream>>>(mixed, cwt, cu, qbuf, kbuf, vbuf);
    // 4) chunked gated delta rule, dv-split x4 -> obuf (aliases dead mixed)
    delta_chunk<<<NSEQ * HV * 4, 256, 0, stream>>>(qbuf, kbuf, vbuf, lgbuf, bbuf, cu, obuf);
    // 5) z = H @ W_z^T (aliases dead q+k) MFMA
    gemm_mfma<<<dim3(VAL_DIM / 128, TOTAL / 128), 256, 0, stream>>>(
        Hb, Wzb, zbuf, TOTAL, VAL_DIM, HIDDEN);
    // 6) gated RMSNorm -> obf (bf16)
    gated_norm<<<TOTAL * HV / 4, 256, 0, stream>>>(obuf, zbuf, nw, obf);
    // 7) out = obf @ W_out^T -> fp32 d_out, MFMA
    gemm_mfma<<<dim3(HIDDEN / 128, TOTAL / 128), 256, 0, stream>>>(
        obf, Woutb, out, TOTAL, HIDDEN, VAL_DIM);
}

// Round 9
// 329.790 us; speedup vs baseline: 6.3010x; 1.1193x over previous
//
#include <hip/hip_runtime.h>
#include <hip/hip_bf16.h>
#include <cstddef>

// Problem constants (fixed by setup_inputs)
#define TOTAL   1536
#define HIDDEN  1024
#define HK      8
#define HV      16
#define DK      64
#define DV      64
#define KSZ     4
#define KEY_DIM 512
#define VAL_DIM 1024
#define CONV_DIM 2048
#define NSEQ    4
#define MAXCH   27   // max total chunks: sum ceil(len/64) <= 1536/64 + 3

typedef unsigned short bfu;  // bf16 bits
typedef _Float16 f16;
typedef __attribute__((ext_vector_type(8))) short bf16x8;
typedef __attribute__((ext_vector_type(4))) float f32x4;
typedef __attribute__((ext_vector_type(4))) _Float16 f16x4;

__device__ __forceinline__ bfu f2b(float f) {  // RNE
    unsigned x = __float_as_uint(f);
    return (bfu)((x + 0x7FFFu + ((x >> 16) & 1u)) >> 16);
}

// ---------------------------------------------------------------------------
// fp32 -> bf16 pack
// ---------------------------------------------------------------------------
__global__ __launch_bounds__(256) void to_bf16(const float* __restrict__ src,
                                               bfu* __restrict__ dst, int n) {
    int idx = (blockIdx.x * 256 + threadIdx.x) * 4;
    if (idx < n) {
        float4 v = *(const float4*)(src + idx);
        ushort4 o;
        o.x = f2b(v.x); o.y = f2b(v.y); o.z = f2b(v.z); o.w = f2b(v.w);
        *(ushort4*)(dst + idx) = o;
    }
}

// ---------------------------------------------------------------------------
// MFMA GEMM: C[M,N] = A[M,K] @ B[N,K]^T.  A,B bf16, C fp32. (unchanged R8)
// ---------------------------------------------------------------------------
#define LDK 72
__global__ __launch_bounds__(256) void gemm_mfma(const bfu* __restrict__ A,
                                                 const bfu* __restrict__ B,
                                                 float* __restrict__ C,
                                                 int M, int N, int K) {
    __shared__ bfu As[128 * LDK];
    __shared__ bfu Bs[128 * LDK];
    const int tid = threadIdx.x;
    const int m0 = blockIdx.y * 128, n0 = blockIdx.x * 128;
    const int lane = tid & 63, w = tid >> 6;
    const int wm = (w >> 1) * 64, wn = (w & 1) * 64;
    const int fr = lane & 15;
    const int fk = (lane >> 4) * 8;
    const int sr = tid >> 1;
    const int sc = (tid & 1) * 32;

    f32x4 acc[4][4];
#pragma unroll
    for (int i = 0; i < 4; ++i)
#pragma unroll
        for (int j = 0; j < 4; ++j) acc[i][j] = (f32x4){0.f, 0.f, 0.f, 0.f};

    for (int kk = 0; kk < K; kk += 64) {
        const bfu* ga = A + (size_t)(m0 + sr) * K + kk + sc;
        const bfu* gb = B + (size_t)(n0 + sr) * K + kk + sc;
        uint4 a0 = *(const uint4*)(ga + 0);
        uint4 a1 = *(const uint4*)(ga + 8);
        uint4 a2 = *(const uint4*)(ga + 16);
        uint4 a3 = *(const uint4*)(ga + 24);
        uint4 b0 = *(const uint4*)(gb + 0);
        uint4 b1 = *(const uint4*)(gb + 8);
        uint4 b2 = *(const uint4*)(gb + 16);
        uint4 b3 = *(const uint4*)(gb + 24);
        __syncthreads();
        *(uint4*)&As[sr * LDK + sc + 0]  = a0;
        *(uint4*)&As[sr * LDK + sc + 8]  = a1;
        *(uint4*)&As[sr * LDK + sc + 16] = a2;
        *(uint4*)&As[sr * LDK + sc + 24] = a3;
        *(uint4*)&Bs[sr * LDK + sc + 0]  = b0;
        *(uint4*)&Bs[sr * LDK + sc + 8]  = b1;
        *(uint4*)&Bs[sr * LDK + sc + 16] = b2;
        *(uint4*)&Bs[sr * LDK + sc + 24] = b3;
        __syncthreads();

#pragma unroll
        for (int k2 = 0; k2 < 64; k2 += 32) {
            bf16x8 af[4], bfr[4];
#pragma unroll
            for (int i = 0; i < 4; ++i)
                af[i] = *(const bf16x8*)&As[(wm + i * 16 + fr) * LDK + k2 + fk];
#pragma unroll
            for (int j = 0; j < 4; ++j)
                bfr[j] = *(const bf16x8*)&Bs[(wn + j * 16 + fr) * LDK + k2 + fk];
#pragma unroll
            for (int i = 0; i < 4; ++i)
#pragma unroll
                for (int j = 0; j < 4; ++j)
                    acc[i][j] = __builtin_amdgcn_mfma_f32_16x16x32_bf16(
                        af[i], bfr[j], acc[i][j], 0, 0, 0);
        }
    }

    const int er = (lane >> 4) * 4;
#pragma unroll
    for (int i = 0; i < 4; ++i)
#pragma unroll
        for (int j = 0; j < 4; ++j) {
            const int col = n0 + wn + j * 16 + fr;
#pragma unroll
            for (int r = 0; r < 4; ++r) {
                const int row = m0 + wm + i * 16 + er + r;
                C[(size_t)row * N + col] = acc[i][j][r];
            }
        }
}

// ---------------------------------------------------------------------------
// b/a projections: beta = sigmoid(b); lg = -exp(A_log)*softplus(a+dt_bias)
// ---------------------------------------------------------------------------
__global__ __launch_bounds__(64) void proj_ba(const float* __restrict__ H,
                                              const float* __restrict__ Wb,
                                              const float* __restrict__ Wa,
                                              const float* __restrict__ dtb,
                                              const float* __restrict__ Alog,
                                              float* __restrict__ betab,
                                              float* __restrict__ lgb) {
    const int tok = blockIdx.x;
    const int lane = threadIdx.x;
    if (lane >= 32) return;
    const float* w = (lane < 16) ? (Wb + (size_t)lane * HIDDEN)
                                 : (Wa + (size_t)(lane - 16) * HIDDEN);
    const float4* wp = (const float4*)w;
    const float4* hp = (const float4*)(H + (size_t)tok * HIDDEN);
    float s = 0.f;
    for (int i = 0; i < HIDDEN / 4; ++i) {
        float4 a = hp[i], c = wp[i];
        s += a.x * c.x + a.y * c.y + a.z * c.z + a.w * c.w;
    }
    if (lane < 16) {
        betab[tok * HV + lane] = 1.f / (1.f + expf(-s));
    } else {
        int hh = lane - 16;
        float x = s + dtb[hh];
        float sp = (x > 20.f) ? x : log1pf(expf(x));
        lgb[tok * HV + hh] = -expf(Alog[hh]) * sp;
    }
}

// ---------------------------------------------------------------------------
// Causal depthwise conv(K=4) + silu, per-head L2 norm of q,k. Block per token.
// ---------------------------------------------------------------------------
__global__ __launch_bounds__(256) void conv_norm(const float* __restrict__ mixed,
                                                 const float* __restrict__ cw,
                                                 const int* __restrict__ cu,
                                                 float* __restrict__ qb,
                                                 float* __restrict__ kb,
                                                 float* __restrict__ vb) {
    const int tok = blockIdx.x;
    const int tid = threadIdx.x;
    __shared__ float yl[CONV_DIM];
    __shared__ float scale[16];

    int b = 0;
    for (int i = 1; i < NSEQ; ++i)
        if (tok >= cu[i]) b = i;
    const int pos = tok - cu[b];

    for (int c = tid; c < CONV_DIM; c += 256) {
        float acc = 0.f;
#pragma unroll
        for (int j = 0; j < KSZ; ++j) {
            int off = j - (KSZ - 1);
            float x = (pos + off >= 0) ? mixed[(size_t)(tok + off) * CONV_DIM + c] : 0.f;
            acc += cw[c * KSZ + j] * x;
        }
        yl[c] = acc / (1.f + expf(-acc));  // silu
    }
    __syncthreads();

    if (tid < 16) {
        float p = 0.f;
        for (int u = 0; u < 64; ++u) {
            float v = yl[tid * 64 + u];
            p += v * v;
        }
        scale[tid] = rsqrtf(p + 1e-6f);
    }
    __syncthreads();

    for (int c = tid; c < CONV_DIM; c += 256) {
        float y = yl[c];
        if (c < KEY_DIM) {
            qb[(size_t)tok * KEY_DIM + c] = y * scale[c >> 6] * 0.125f;  // * DK^-0.5
        } else if (c < 2 * KEY_DIM) {
            kb[(size_t)tok * KEY_DIM + (c - KEY_DIM)] = y * scale[c >> 6];
        } else {
            vb[(size_t)tok * VAL_DIM + (c - 2 * KEY_DIM)] = y;
        }
    }
}

// ---------------------------------------------------------------------------
// Delta phase 1 (fully chunk-parallel). Block = (chunk, head).
// A = tril(be^{dc}KK^T,-1); solve (I+A)X=[b*V | b*e*K] -> X=[W|Y];
// P = tril(e^{dc}QK^T,0); outputs: PW->ob, Z=e*Q-PY (f16),
// H=(dsc*K)^T W (f16), G=e63*I-(dsc*K)^T Y (f16).
// ---------------------------------------------------------------------------
#define SK 68    // KlT/QlT/Am row stride (floats)
#define SX 132   // X row stride (floats), 128 cols + pad
__global__ __launch_bounds__(256) void delta_phase1(
        const float* __restrict__ qb, const float* __restrict__ kb,
        const float* __restrict__ vb, const float* __restrict__ lgb,
        const float* __restrict__ betab, const int* __restrict__ cu,
        float* __restrict__ ob, f16* __restrict__ Gg,
        f16* __restrict__ Hg, f16* __restrict__ Zg) {
    const int c = blockIdx.x >> 4;
    const int h = blockIdx.x & 15;
    const int hk = h >> 1;
    int b = -1, base = 0, t1 = 0, cs = 0;
    for (int i = 0; i < NSEQ; ++i) {
        int len = cu[i + 1] - cu[i];
        int nb = (len + 63) >> 6;
        if (b < 0) {
            if (c < cs + nb) { b = i; base = cu[i] + (c - cs) * 64; t1 = cu[i + 1]; }
            else cs += nb;
        }
    }
    if (b < 0) return;
    const size_t slot = (size_t)blockIdx.x * 4096;

    const int tid = threadIdx.x;
    const int lane = tid & 63, w = tid >> 6;
    const int tm = tid >> 4, tn = tid & 15;

    __shared__ float KlT[64 * SK];
    __shared__ float QlT[64 * SK];
    __shared__ float Am[64 * SK];
    __shared__ float X[64 * SX];
    __shared__ float cl[64], el[64], bl[64], lgl[64], dscl[64];

    // ---- stage K,Q transposed; keep k,v rows in regs for RHS ----
    const int tt = tid >> 2;
    const int d0 = (tid & 3) << 4;
    const int tau0 = base + tt;
    const bool valid = tau0 < t1;
    const float4 z4 = {0.f, 0.f, 0.f, 0.f};
    float4 kv[4], vv[4];
#pragma unroll
    for (int u4 = 0; u4 < 4; ++u4) {
        const int d = d0 + u4 * 4;
        kv[u4] = valid ? *(const float4*)&kb[(size_t)tau0 * KEY_DIM + hk * 64 + d] : z4;
        float4 qv = valid ? *(const float4*)&qb[(size_t)tau0 * KEY_DIM + hk * 64 + d] : z4;
        vv[u4] = valid ? *(const float4*)&vb[(size_t)tau0 * VAL_DIM + h * 64 + d] : z4;
        KlT[(d + 0) * SK + tt] = kv[u4].x; KlT[(d + 1) * SK + tt] = kv[u4].y;
        KlT[(d + 2) * SK + tt] = kv[u4].z; KlT[(d + 3) * SK + tt] = kv[u4].w;
        QlT[(d + 0) * SK + tt] = qv.x; QlT[(d + 1) * SK + tt] = qv.y;
        QlT[(d + 2) * SK + tt] = qv.z; QlT[(d + 3) * SK + tt] = qv.w;
    }
    if (tid < 64) {
        const int ta = base + tid;
        const bool v2 = ta < t1;
        lgl[tid] = v2 ? lgb[ta * HV + h] : 0.f;
        bl[tid]  = v2 ? betab[ta * HV + h] : 0.f;
    }
    __syncthreads();

    // ---- wave 0: inclusive scan -> c, e=exp(c), dsc=exp(c63-c) ----
    if (w == 0) {
        float x = lgl[lane];
#pragma unroll
        for (int off = 1; off < 64; off <<= 1) {
            float y = __shfl_up(x, off);
            if (lane >= off) x += y;
        }
        cl[lane] = x;
        el[lane] = expf(x);
        float c63 = __shfl(x, 63);
        dscl[lane] = expf(c63 - x);
    }
    __syncthreads();

    // ---- RHS fill: X[t][0:64]=b*V, X[t][64:128]=b*e*K ----
    {
        const float bt = bl[tt], bet = bl[tt] * el[tt];
#pragma unroll
        for (int u4 = 0; u4 < 4; ++u4) {
            const int d = d0 + u4 * 4;
            float4 r1 = {bt * vv[u4].x, bt * vv[u4].y, bt * vv[u4].z, bt * vv[u4].w};
            float4 r2 = {bet * kv[u4].x, bet * kv[u4].y, bet * kv[u4].z, bet * kv[u4].w};
            *(float4*)&X[tt * SX + d] = r1;
            *(float4*)&X[tt * SX + 64 + d] = r2;
        }
    }
    // ---- A-gram ----
    {
        float a[4][4] = {};
        for (int d = 0; d < 64; ++d) {
            float4 kt = *(const float4*)&KlT[d * SK + tm * 4];
            float4 ks = *(const float4*)&KlT[d * SK + tn * 4];
            float ktr[4] = {kt.x, kt.y, kt.z, kt.w};
            float ksr[4] = {ks.x, ks.y, ks.z, ks.w};
#pragma unroll
            for (int i = 0; i < 4; ++i)
#pragma unroll
                for (int j = 0; j < 4; ++j) a[i][j] += ktr[i] * ksr[j];
        }
#pragma unroll
        for (int i = 0; i < 4; ++i) {
            const int t = tm * 4 + i;
#pragma unroll
            for (int j = 0; j < 4; ++j) {
                const int s = tn * 4 + j;
                Am[t * SK + s] = (s < t) ? bl[t] * expf(cl[t] - cl[s]) * a[i][j] : 0.f;
            }
        }
    }
    __syncthreads();

    // ---- blocked forward substitution on X (128 RHS cols) ----
#pragma unroll
    for (int ib = 0; ib < 4; ++ib) {
        if (tid < 128) {  // col j = tid, serial diag solve with reg cache
            float xr[16];
#pragma unroll
            for (int i = 0; i < 16; ++i) {
                const int t = ib * 16 + i;
                float acc = X[t * SX + tid];
#pragma unroll
                for (int s = 0; s < 16; ++s)
                    if (s < i) acc -= Am[t * SK + ib * 16 + s] * xr[s];
                xr[i] = acc;
                X[t * SX + tid] = acc;
            }
        }
        __syncthreads();
        if (ib < 3) {
            const int j = tid & 127;
            const int rh = tid >> 7;
            float us[16];
#pragma unroll
            for (int s = 0; s < 16; ++s) us[s] = X[(ib * 16 + s) * SX + j];
            for (int r = (ib + 1) * 16 + rh; r < 64; r += 2) {
                float acc = X[r * SX + j];
#pragma unroll
                for (int s = 0; s < 16; ++s)
                    acc -= Am[r * SK + ib * 16 + s] * us[s];
                X[r * SX + j] = acc;
            }
            __syncthreads();
        }
    }
    __syncthreads();  // fwd-sub fully done reading Am

    // ---- P-gram into Am ----
    {
        float a[4][4] = {};
        for (int d = 0; d < 64; ++d) {
            float4 qt = *(const float4*)&QlT[d * SK + tm * 4];
            float4 ks = *(const float4*)&KlT[d * SK + tn * 4];
            float qtr[4] = {qt.x, qt.y, qt.z, qt.w};
            float ksr[4] = {ks.x, ks.y, ks.z, ks.w};
#pragma unroll
            for (int i = 0; i < 4; ++i)
#pragma unroll
                for (int j = 0; j < 4; ++j) a[i][j] += qtr[i] * ksr[j];
        }
#pragma unroll
        for (int i = 0; i < 4; ++i) {
            const int t = tm * 4 + i;
#pragma unroll
            for (int j = 0; j < 4; ++j) {
                const int s = tn * 4 + j;
                Am[t * SK + s] = (s <= t) ? expf(cl[t] - cl[s]) * a[i][j] : 0.f;
            }
        }
    }
    __syncthreads();

    // ---- PW -> ob ----
    {
        float acc[4][4] = {};
        for (int s4 = 0; s4 < 16; ++s4) {
            float4 u0 = *(const float4*)&X[(s4 * 4 + 0) * SX + tn * 4];
            float4 u1 = *(const float4*)&X[(s4 * 4 + 1) * SX + tn * 4];
            float4 u2 = *(const float4*)&X[(s4 * 4 + 2) * SX + tn * 4];
            float4 u3 = *(const float4*)&X[(s4 * 4 + 3) * SX + tn * 4];
#pragma unroll
            for (int i = 0; i < 4; ++i) {
                float4 p4 = *(const float4*)&Am[(tm * 4 + i) * SK + s4 * 4];
                acc[i][0] += p4.x * u0.x + p4.y * u1.x + p4.z * u2.x + p4.w * u3.x;
                acc[i][1] += p4.x * u0.y + p4.y * u1.y + p4.z * u2.y + p4.w * u3.y;
                acc[i][2] += p4.x * u0.z + p4.y * u1.z + p4.z * u2.z + p4.w * u3.z;
                acc[i][3] += p4.x * u0.w + p4.y * u1.w + p4.z * u2.w + p4.w * u3.w;
            }
        }
#pragma unroll
        for (int i = 0; i < 4; ++i) {
            const int tau = base + tm * 4 + i;
            if (tau < t1) {
                float4 v = {acc[i][0], acc[i][1], acc[i][2], acc[i][3]};
                *(float4*)&ob[(size_t)tau * VAL_DIM + h * 64 + tn * 4] = v;
            }
        }
    }
    // ---- Z = e*Q - P@Y -> Zg (f16) ----
    {
        float acc[4][4] = {};
        for (int s4 = 0; s4 < 16; ++s4) {
            float4 u0 = *(const float4*)&X[(s4 * 4 + 0) * SX + 64 + tn * 4];
            float4 u1 = *(const float4*)&X[(s4 * 4 + 1) * SX + 64 + tn * 4];
            float4 u2 = *(const float4*)&X[(s4 * 4 + 2) * SX + 64 + tn * 4];
            float4 u3 = *(const float4*)&X[(s4 * 4 + 3) * SX + 64 + tn * 4];
#pragma unroll
            for (int i = 0; i < 4; ++i) {
                float4 p4 = *(const float4*)&Am[(tm * 4 + i) * SK + s4 * 4];
                acc[i][0] += p4.x * u0.x + p4.y * u1.x + p4.z * u2.x + p4.w * u3.x;
                acc[i][1] += p4.x * u0.y + p4.y * u1.y + p4.z * u2.y + p4.w * u3.y;
                acc[i][2] += p4.x * u0.z + p4.y * u1.z + p4.z * u2.z + p4.w * u3.z;
                acc[i][3] += p4.x * u0.w + p4.y * u1.w + p4.z * u2.w + p4.w * u3.w;
            }
        }
#pragma unroll
        for (int i = 0; i < 4; ++i) {
            const int t = tm * 4 + i;
            f16x4 zh;
#pragma unroll
            for (int j = 0; j < 4; ++j) {
                const int d = tn * 4 + j;
                zh[j] = (f16)(el[t] * QlT[d * SK + t] - acc[i][j]);
            }
            *(f16x4*)&Zg[slot + t * 64 + tn * 4] = zh;
        }
    }
    // ---- H = (dsc*K)^T W -> Hg; G = e63*I - (dsc*K)^T Y -> Gg ----
    {
        float accH[4][4] = {};
        float accG[4][4] = {};
        for (int s4 = 0; s4 < 16; ++s4) {
            float4 d4 = *(const float4*)&dscl[s4 * 4];
            float4 w0 = *(const float4*)&X[(s4 * 4 + 0) * SX + tn * 4];
            float4 w1 = *(const float4*)&X[(s4 * 4 + 1) * SX + tn * 4];
            float4 w2 = *(const float4*)&X[(s4 * 4 + 2) * SX + tn * 4];
            float4 w3 = *(const float4*)&X[(s4 * 4 + 3) * SX + tn * 4];
            float4 y0 = *(const float4*)&X[(s4 * 4 + 0) * SX + 64 + tn * 4];
            float4 y1 = *(const float4*)&X[(s4 * 4 + 1) * SX + 64 + tn * 4];
            float4 y2 = *(const float4*)&X[(s4 * 4 + 2) * SX + 64 + tn * 4];
            float4 y3 = *(const float4*)&X[(s4 * 4 + 3) * SX + 64 + tn * 4];
#pragma unroll
            for (int i = 0; i < 4; ++i) {
                float4 k4 = *(const float4*)&KlT[(tm * 4 + i) * SK + s4 * 4];
                float k0 = k4.x * d4.x, k1 = k4.y * d4.y, k2 = k4.z * d4.z, k3 = k4.w * d4.w;
                accH[i][0] += k0 * w0.x + k1 * w1.x + k2 * w2.x + k3 * w3.x;
                accH[i][1] += k0 * w0.y + k1 * w1.y + k2 * w2.y + k3 * w3.y;
                accH[i][2] += k0 * w0.z + k1 * w1.z + k2 * w2.z + k3 * w3.z;
                accH[i][3] += k0 * w0.w + k1 * w1.w + k2 * w2.w + k3 * w3.w;
                accG[i][0] += k0 * y0.x + k1 * y1.x + k2 * y2.x + k3 * y3.x;
                accG[i][1] += k0 * y0.y + k1 * y1.y + k2 * y2.y + k3 * y3.y;
                accG[i][2] += k0 * y0.z + k1 * y1.z + k2 * y2.z + k3 * y3.z;
                accG[i][3] += k0 * y0.w + k1 * y1.w + k2 * y2.w + k3 * y3.w;
            }
        }
        const float e63v = el[63];
#pragma unroll
        for (int i = 0; i < 4; ++i) {
            const int d = tm * 4 + i;
            f16x4 hh, gg;
#pragma unroll
            for (int j = 0; j < 4; ++j) {
                const int e = tn * 4 + j;
                hh[j] = (f16)accH[i][j];
                gg[j] = (f16)(((d == e) ? e63v : 0.f) - accG[i][j]);
            }
            *(f16x4*)&Hg[slot + d * 64 + tn * 4] = hh;
            *(f16x4*)&Gg[slot + d * 64 + tn * 4] = gg;
        }
    }
}

// ---------------------------------------------------------------------------
// Delta phase 2 (sequential scan). Block = (seq, head).
// For each chunk: ob += Z*S; S <- G*S + H (S in LDS dbuf).
// ---------------------------------------------------------------------------
__global__ __launch_bounds__(256) void delta_phase2(
        const int* __restrict__ cu, const f16* __restrict__ Gg,
        const f16* __restrict__ Hg, const f16* __restrict__ Zg,
        float* __restrict__ ob) {
    const int b = blockIdx.x >> 4, h = blockIdx.x & 15;
    const int tid = threadIdx.x;
    const int tm = tid >> 4, tn = tid & 15;
    __shared__ float Sb[2][64 * SK];
    __shared__ float Gs[64 * SK];
    __shared__ float Zs[64 * SK];

    int cs = 0;
    for (int i = 0; i < NSEQ; ++i) {
        if (i < b) cs += ((cu[i + 1] - cu[i]) + 63) >> 6;
    }
    const int t0 = cu[b], t1 = cu[b + 1];
    const int nb = (t1 - t0 + 63) >> 6;

    for (int i = tid; i < 64 * SK; i += 256) Sb[0][i] = 0.f;
    int cur = 0;
    __syncthreads();

    for (int ci = 0; ci < nb; ++ci) {
        const size_t slot = (size_t)((cs + ci) * 16 + h) * 4096;
        const int base = t0 + ci * 64;

        // stage G,Z (f16 -> fp32 LDS)
        for (int e = tid * 4; e < 4096; e += 1024) {
            f16x4 g4 = *(const f16x4*)&Gg[slot + e];
            f16x4 z4 = *(const f16x4*)&Zg[slot + e];
            const int r = e >> 6, cc = e & 63;
            float4 gf = {(float)g4[0], (float)g4[1], (float)g4[2], (float)g4[3]};
            float4 zf = {(float)z4[0], (float)z4[1], (float)z4[2], (float)z4[3]};
            *(float4*)&Gs[r * SK + cc] = gf;
            *(float4*)&Zs[r * SK + cc] = zf;
        }
        __syncthreads();

        // O-phase: ob[t] += Z[t][:] @ S
        {
            float acc[4][4];
#pragma unroll
            for (int i = 0; i < 4; ++i) {
                const int tau = base + tm * 4 + i;
                if (tau < t1) {
                    float4 o4 = *(const float4*)&ob[(size_t)tau * VAL_DIM + h * 64 + tn * 4];
                    acc[i][0] = o4.x; acc[i][1] = o4.y; acc[i][2] = o4.z; acc[i][3] = o4.w;
                } else {
                    acc[i][0] = acc[i][1] = acc[i][2] = acc[i][3] = 0.f;
                }
            }
            for (int s4 = 0; s4 < 16; ++s4) {
                float4 u0 = *(const float4*)&Sb[cur][(s4 * 4 + 0) * SK + tn * 4];
                float4 u1 = *(const float4*)&Sb[cur][(s4 * 4 + 1) * SK + tn * 4];
                float4 u2 = *(const float4*)&Sb[cur][(s4 * 4 + 2) * SK + tn * 4];
                float4 u3 = *(const float4*)&Sb[cur][(s4 * 4 + 3) * SK + tn * 4];
#pragma unroll
                for (int i = 0; i < 4; ++i) {
                    float4 z4 = *(const float4*)&Zs[(tm * 4 + i) * SK + s4 * 4];
                    acc[i][0] += z4.x * u0.x + z4.y * u1.x + z4.z * u2.x + z4.w * u3.x;
                    acc[i][1] += z4.x * u0.y + z4.y * u1.y + z4.z * u2.y + z4.w * u3.y;
                    acc[i][2] += z4.x * u0.z + z4.y * u1.z + z4.z * u2.z + z4.w * u3.z;
                    acc[i][3] += z4.x * u0.w + z4.y * u1.w + z4.z * u2.w + z4.w * u3.w;
                }
            }
#pragma unroll
            for (int i = 0; i < 4; ++i) {
                const int tau = base + tm * 4 + i;
                if (tau < t1) {
                    float4 v = {acc[i][0], acc[i][1], acc[i][2], acc[i][3]};
                    *(float4*)&ob[(size_t)tau * VAL_DIM + h * 64 + tn * 4] = v;
                }
            }
        }
        // S-phase: Snxt = G @ Scur + H
        {
            float acc[4][4];
#pragma unroll
            for (int i = 0; i < 4; ++i) {
                f16x4 h4 = *(const f16x4*)&Hg[slot + (tm * 4 + i) * 64 + tn * 4];
                acc[i][0] = (float)h4[0]; acc[i][1] = (float)h4[1];
                acc[i][2] = (float)h4[2]; acc[i][3] = (float)h4[3];
            }
            for (int s4 = 0; s4 < 16; ++s4) {
                float4 u0 = *(const float4*)&Sb[cur][(s4 * 4 + 0) * SK + tn * 4];
                float4 u1 = *(const float4*)&Sb[cur][(s4 * 4 + 1) * SK + tn * 4];
                float4 u2 = *(const float4*)&Sb[cur][(s4 * 4 + 2) * SK + tn * 4];
                float4 u3 = *(const float4*)&Sb[cur][(s4 * 4 + 3) * SK + tn * 4];
#pragma unroll
                for (int i = 0; i < 4; ++i) {
                    float4 g4 = *(const float4*)&Gs[(tm * 4 + i) * SK + s4 * 4];
                    acc[i][0] += g4.x * u0.x + g4.y * u1.x + g4.z * u2.x + g4.w * u3.x;
                    acc[i][1] += g4.x * u0.y + g4.y * u1.y + g4.z * u2.y + g4.w * u3.y;
                    acc[i][2] += g4.x * u0.z + g4.y * u1.z + g4.z * u2.z + g4.w * u3.z;
                    acc[i][3] += g4.x * u0.w + g4.y * u1.w + g4.z * u2.w + g4.w * u3.w;
                }
            }
#pragma unroll
            for (int i = 0; i < 4; ++i) {
                float4 v = {acc[i][0], acc[i][1], acc[i][2], acc[i][3]};
                *(float4*)&Sb[1 - cur][(tm * 4 + i) * SK + tn * 4] = v;
            }
        }
        __syncthreads();
        cur ^= 1;
    }
}

// ---------------------------------------------------------------------------
// Gated RMSNorm: out_bf16 = o * rsqrt(mean(o^2)+eps) * nw * silu(z).
// ---------------------------------------------------------------------------
__global__ __launch_bounds__(256) void gated_norm(const float* __restrict__ ob,
                                                  const float* __restrict__ zb,
                                                  const float* __restrict__ nw,
                                                  bfu* __restrict__ obf) {
    const int wid = blockIdx.x * 4 + (threadIdx.x >> 6);
    const int lane = threadIdx.x & 63;
    const int tok = wid >> 4, h = wid & 15;
    const size_t idx = (size_t)tok * VAL_DIM + h * 64 + lane;
    const float o = ob[idx];
    float ss = o * o;
#pragma unroll
    for (int m = 1; m < 64; m <<= 1) ss += __shfl_xor(ss, m);
    const float r = rsqrtf(ss * (1.f / 64.f) + 1e-6f);
    const float z = zb[idx];
    const float sz = z / (1.f + expf(-z));
    obf[idx] = f2b(o * r * nw[lane] * sz);
}

// ---------------------------------------------------------------------------
extern "C" void kernel_launch(void* const* d_in, const int* in_sizes, int n_in,
                              void* d_out, int out_size, void* d_ws, size_t ws_size,
                              hipStream_t stream) {
    const float* H    = (const float*)d_in[0];
    const float* Wqkv = (const float*)d_in[1];
    const float* Wz   = (const float*)d_in[2];
    const float* Wb   = (const float*)d_in[3];
    const float* Wa   = (const float*)d_in[4];
    const float* cwt  = (const float*)d_in[5];
    const float* dtb  = (const float*)d_in[6];
    const float* Alog = (const float*)d_in[7];
    const float* nw   = (const float*)d_in[8];
    const float* Wout = (const float*)d_in[9];
    const int*   cu   = (const int*)d_in[10];
    float* out = (float*)d_out;

    // --- Workspace (~41.9 MB; envelope >= 44.8 MB) ---
    float* wsf = (float*)d_ws;
    float* mixed = wsf;                                   // gemm1 -> conv
    float* obuf  = wsf;                                   // alias (first half)
    bfu*   obf   = (bfu*)(wsf + (size_t)TOTAL * VAL_DIM); // alias (mixed tail)
    float* qbuf  = wsf + (size_t)TOTAL * CONV_DIM;
    float* kbuf  = qbuf + (size_t)TOTAL * KEY_DIM;
    float* vbuf  = kbuf + (size_t)TOTAL * KEY_DIM;
    float* lgbuf = vbuf + (size_t)TOTAL * VAL_DIM;
    float* bbuf  = lgbuf + (size_t)TOTAL * HV;
    bfu* Hb    = (bfu*)(bbuf + (size_t)TOTAL * HV);
    bfu* Wqkvb = Hb + (size_t)TOTAL * HIDDEN;
    bfu* Wzb   = Wqkvb + (size_t)CONV_DIM * HIDDEN;
    bfu* Woutb = Wzb + (size_t)VAL_DIM * HIDDEN;
    f16* Gg    = (f16*)(Woutb + (size_t)HIDDEN * VAL_DIM); // fresh
    f16* Hg    = Gg + (size_t)MAXCH * 16 * 4096;           // fresh
    f16* Zg    = (f16*)Wqkvb;                              // alias (dead after gemm1)
    float* zbuf = (float*)Gg;                              // alias (dead after phase2)

    // 0) bf16 conversions
    to_bf16<<<(TOTAL * HIDDEN) / 1024, 256, 0, stream>>>(H, Hb, TOTAL * HIDDEN);
    to_bf16<<<(CONV_DIM * HIDDEN) / 1024, 256, 0, stream>>>(Wqkv, Wqkvb, CONV_DIM * HIDDEN);
    to_bf16<<<(VAL_DIM * HIDDEN) / 1024, 256, 0, stream>>>(Wz, Wzb, VAL_DIM * HIDDEN);
    to_bf16<<<(HIDDEN * VAL_DIM) / 1024, 256, 0, stream>>>(Wout, Woutb, HIDDEN * VAL_DIM);

    // 1) mixed = H @ W_qkv^T (MFMA)
    gemm_mfma<<<dim3(CONV_DIM / 128, TOTAL / 128), 256, 0, stream>>>(
        Hb, Wqkvb, mixed, TOTAL, CONV_DIM, HIDDEN);
    // 2) beta / log-gamma
    proj_ba<<<TOTAL, 64, 0, stream>>>(H, Wb, Wa, dtb, Alog, bbuf, lgbuf);
    // 3) conv + silu + l2 norm -> q,k,v
    conv_norm<<<TOTAL, 256, 0, stream>>>(mixed, cwt, cu, qbuf, kbuf, vbuf);
    // 4a) delta phase 1 (chunk-parallel): PW->obuf, G/H/Z f16
    delta_phase1<<<MAXCH * 16, 256, 0, stream>>>(qbuf, kbuf, vbuf, lgbuf, bbuf,
                                                 cu, obuf, Gg, Hg, Zg);
    // 4b) delta phase 2 (sequential scan): obuf += Z*S, S <- G*S+H
    delta_phase2<<<NSEQ * HV, 256, 0, stream>>>(cu, Gg, Hg, Zg, obuf);
    // 5) z = H @ W_z^T (MFMA; zbuf aliases dead Gg/Hg)
    gemm_mfma<<<dim3(VAL_DIM / 128, TOTAL / 128), 256, 0, stream>>>(
        Hb, Wzb, zbuf, TOTAL, VAL_DIM, HIDDEN);
    // 6) gated RMSNorm -> obf (bf16)
    gated_norm<<<TOTAL * HV / 4, 256, 0, stream>>>(obuf, zbuf, nw, obf);
    // 7) out = obf @ W_out^T -> fp32 d_out (MFMA)
    gemm_mfma<<<dim3(HIDDEN / 128, TOTAL / 128), 256, 0, stream>>>(
        obf, Woutb, out, TOTAL, HIDDEN, VAL_DIM);
}